// Round 20
// baseline (80.098 us; speedup 1.0000x reference)
//
#include <hip/hip_runtime.h>
#include <hip/hip_bf16.h>

// attention scale folded with log2(e): softmax exp(x) = exp2(x * log2e)
#define ATT_SCALE_L2E 0.2550322540f   // 32^-0.5 * log2(e)

typedef __attribute__((ext_vector_type(8))) short bf16x8;
typedef __attribute__((ext_vector_type(4))) short bf16x4;
typedef __attribute__((ext_vector_type(4))) float f32x4;
typedef __attribute__((ext_vector_type(16))) float f32x16;
typedef __attribute__((ext_vector_type(4))) int i32x4;

#define MFMA16(a, b, c) __builtin_amdgcn_mfma_f32_16x16x32_bf16(a, b, c, 0, 0, 0)
#define MFMA32(a, b, c) __builtin_amdgcn_mfma_f32_32x32x16_bf16(a, b, c, 0, 0, 0)

__device__ inline short f2b(float f) {
    return __builtin_bit_cast(short, __float2bfloat16(f));
}

// packed f32x2 -> bf16x2 in one instruction
__device__ inline int cvt_pk(float a, float b) {
    int r;
    asm("v_cvt_pk_bf16_f32 %0, %1, %2" : "=v"(r) : "v"(a), "v"(b));
    return r;
}

// ---------------------------------------------------------------------------
// K0a: w_qkv fp32 -> bf16
// ---------------------------------------------------------------------------
__global__ __launch_bounds__(256) void wconv_k(const float* __restrict__ w,
                                               short* __restrict__ wb) {
    int i0 = (blockIdx.x * 256 + threadIdx.x) * 8;
    float4 lo = *(const float4*)(w + i0);
    float4 hi = *(const float4*)(w + i0 + 4);
    bf16x8 o;
    o[0] = f2b(lo.x); o[1] = f2b(lo.y); o[2] = f2b(lo.z); o[3] = f2b(lo.w);
    o[4] = f2b(hi.x); o[5] = f2b(hi.y); o[6] = f2b(hi.z); o[7] = f2b(hi.w);
    *(bf16x8*)(wb + i0) = o;
}

// ---------------------------------------------------------------------------
// K0b: fused downsample + transpose + bf16: xt[b][n][c]
// ---------------------------------------------------------------------------
__global__ __launch_bounds__(256) void xt_k(const float* __restrict__ x,
                                            short* __restrict__ xt) {
    int b = blockIdx.y;
    int t = threadIdx.x;
    int n = blockIdx.x * 32 + (t >> 3);
    const float* xb = x + (size_t)b * 1048576 + (n >> 5) * 128 + (n & 31) * 2;
    short* dst = xt + ((size_t)b * 1024 + n) * 256;
#pragma unroll
    for (int it = 0; it < 4; ++it) {
        int c = (t & 7) * 8 + it * 64;
        bf16x8 o;
#pragma unroll
        for (int j = 0; j < 8; ++j) o[j] = f2b(xb[(size_t)(c + j) * 4096]);
        *(bf16x8*)(dst + c) = o;
    }
}

// ---------------------------------------------------------------------------
// K1: QKV MFMA GEMM (LDS-free main loop), epilogue transpose (r11, verified).
// ---------------------------------------------------------------------------
__global__ __launch_bounds__(256) void qkv_k(const short* __restrict__ wb,
                                             const short* __restrict__ xt,
                                             short* __restrict__ qt,
                                             short* __restrict__ ktr,
                                             short* __restrict__ vvr) {
    int b = blockIdx.x;
    int ntile = blockIdx.y * 128;
    int otile = blockIdx.z * 64;
    int t = threadIdx.x;
    int w = t >> 6, l = t & 63, g = l >> 4, li = l & 15;
    int oh = (w & 1) * 32, mh = (w >> 1) * 64;
    int o_base = otile + oh;
    int head = o_base / 96;
    int role = (o_base >> 5) % 3;  // 0=q 1=k 2=v
    size_t bh = (size_t)b * 8 + head;

    const short* arow = wb + (size_t)o_base * 256;
    const short* brow = xt + ((size_t)b * 1024 + ntile + mh) * 256;

    f32x4 zero = {0.f, 0.f, 0.f, 0.f};
    f32x4 acc[2][4];
#pragma unroll
    for (int og = 0; og < 2; ++og)
#pragma unroll
        for (int mg = 0; mg < 4; ++mg) acc[og][mg] = zero;

#pragma unroll
    for (int kc = 0; kc < 256; kc += 32) {
        bf16x8 af[2], bf_[4];
#pragma unroll
        for (int og = 0; og < 2; ++og)
            af[og] = *(const bf16x8*)(arow + (size_t)(og * 16 + li) * 256 + kc + 8 * g);
#pragma unroll
        for (int mg = 0; mg < 4; ++mg)
            bf_[mg] = *(const bf16x8*)(brow + (size_t)(mg * 16 + li) * 256 + kc + 8 * g);
#pragma unroll
        for (int og = 0; og < 2; ++og)
#pragma unroll
            for (int mg = 0; mg < 4; ++mg)
                acc[og][mg] = MFMA16(af[og], bf_[mg], acc[og][mg]);
    }

    __shared__ short Tl[4][32][64];
    short (*Tw)[64] = Tl[w];
    float sc = (role == 0) ? ATT_SCALE_L2E : 1.f;

#pragma unroll
    for (int og = 0; og < 2; ++og)
#pragma unroll
        for (int mg = 0; mg < 4; ++mg)
#pragma unroll
            for (int r = 0; r < 4; ++r) {
                int op = og * 16 + 4 * g + r;
                int qp = (op >> 3) & 3;
                Tw[op][(mg * 16 + li) ^ (qp << 4)] = f2b(acc[og][mg][r] * sc);
            }
    __syncthreads();

    if (role == 0) {
#pragma unroll
        for (int it = 0; it < 4; ++it) {
            int s = it * 64 + l;
            int dq = (l & 3) * 8;
            int n = s >> 2;
            int q2 = dq >> 3;
            bf16x8 vo;
#pragma unroll
            for (int j = 0; j < 8; ++j)
                vo[j] = Tw[dq + j][n ^ (q2 << 4)];
            *(bf16x8*)(qt + ((size_t)bh * 1024 + ntile + mh + n) * 32 + dq) = vo;
        }
    } else if (role == 1) {
        int base_jb = (ntile + mh) >> 5;
#pragma unroll
        for (int it = 0; it < 4; ++it) {
            int s = it * 64 + l;
            int il2 = s & 31;
            int combo = (s >> 5) & 3;
            int jbr = s >> 7;
            int dq = combo * 8;
            int n_rel = jbr * 32 + il2;
            bf16x8 vo;
#pragma unroll
            for (int j = 0; j < 8; ++j)
                vo[j] = Tw[dq + j][n_rel ^ (combo << 4)];
            *(bf16x8*)(ktr + (size_t)bh * 32768 +
                       (size_t)(base_jb + jbr) * 1024 + combo * 256 + il2 * 8) = vo;
        }
    } else {
        int base_jb = (ntile + mh) >> 5;
#pragma unroll
        for (int it = 0; it < 4; ++it) {
            int s = it * 64 + l;
            int il2 = s & 31;
            int combo = (s >> 5) & 3;
            int jbr = s >> 7;
            int pan = combo >> 1, hi2 = combo & 1;
            int q2 = (il2 >> 3) & 3;
            int bn = jbr * 32 + pan * 16 + 4 * hi2;
            bf16x8 vo;
#pragma unroll
            for (int j = 0; j < 4; ++j) vo[j] = Tw[il2][(bn + j) ^ (q2 << 4)];
#pragma unroll
            for (int j = 0; j < 4; ++j) vo[4 + j] = Tw[il2][(bn + 8 + j) ^ (q2 << 4)];
            *(bf16x8*)(vvr + (size_t)bh * 32768 +
                       (size_t)(base_jb + jbr) * 1024 + combo * 256 + il2 * 8) = vo;
        }
    }
}

// ---------------------------------------------------------------------------
// K2: attention (r11 core, verified best) + T5 s_setprio around MFMA clusters
// (m191 precedent: +4-7% on attn with independent waves; zero correctness
// risk — pure scheduler hint). Output ao2[b][c][n].
// ---------------------------------------------------------------------------
__global__ __launch_bounds__(512) void attn_k(const short* __restrict__ qt,
                                              const short* __restrict__ ktr,
                                              const short* __restrict__ vvr,
                                              float* __restrict__ ao2) {
    int bh = blockIdx.x;
    int b = bh >> 3, h = bh & 7;
    int t = threadIdx.x;
    int w = t >> 6, l = t & 63;
    int il = l & 31, hi = l >> 5;
    int wq = w & 3, jh = w >> 2;
    int ibase = blockIdx.y * 128 + wq * 32;

    const short* qtb = qt + (size_t)bh * 32768;
    const short* kbase = ktr + (size_t)bh * 32768 + jh * 16384 + hi * 256 + il * 8;
    const short* vbase = vvr + (size_t)bh * 32768 + jh * 16384 + hi * 256 + il * 8;

    bf16x8 qf0 = *(const bf16x8*)(qtb + (size_t)(ibase + il) * 32 + 8 * hi);
    bf16x8 qf1 = *(const bf16x8*)(qtb + (size_t)(ibase + il) * 32 + 16 + 8 * hi);

    f32x16 zero16 = {0.f,0.f,0.f,0.f,0.f,0.f,0.f,0.f,0.f,0.f,0.f,0.f,0.f,0.f,0.f,0.f};
    f32x16 oacc = zero16;
    float lr0 = 0.f, lr1 = 0.f, lr2 = 0.f, lr3 = 0.f;

#pragma unroll 2
    for (int jb = 0; jb < 16; ++jb) {
        const short* kp = kbase + (size_t)jb * 1024;
        const short* vp = vbase + (size_t)jb * 1024;
        bf16x8 kf0 = *(const bf16x8*)(kp);
        bf16x8 kf1 = *(const bf16x8*)(kp + 512);
        __builtin_amdgcn_s_setprio(1);
        f32x16 s = MFMA32(kf0, qf0, zero16);
        s = MFMA32(kf1, qf1, s);
        __builtin_amdgcn_s_setprio(0);

        float p[16];
#pragma unroll
        for (int r = 0; r < 16; ++r) p[r] = exp2f(s[r]);
        lr0 += p[0] + p[4] + p[8]  + p[12];
        lr1 += p[1] + p[5] + p[9]  + p[13];
        lr2 += p[2] + p[6] + p[10] + p[14];
        lr3 += p[3] + p[7] + p[11] + p[15];

        i32x4 fa, fb;
        fa[0] = cvt_pk(p[0], p[1]);   fa[1] = cvt_pk(p[2], p[3]);
        fa[2] = cvt_pk(p[4], p[5]);   fa[3] = cvt_pk(p[6], p[7]);
        fb[0] = cvt_pk(p[8], p[9]);   fb[1] = cvt_pk(p[10], p[11]);
        fb[2] = cvt_pk(p[12], p[13]); fb[3] = cvt_pk(p[14], p[15]);
        bf16x8 pfa = __builtin_bit_cast(bf16x8, fa);
        bf16x8 pfb = __builtin_bit_cast(bf16x8, fb);

        bf16x8 vfa = *(const bf16x8*)(vp);
        bf16x8 vfb = *(const bf16x8*)(vp + 512);
        __builtin_amdgcn_s_setprio(1);
        oacc = MFMA32(vfa, pfa, oacc);
        oacc = MFMA32(vfb, pfb, oacc);
        __builtin_amdgcn_s_setprio(0);
    }

    float lrun = (lr0 + lr1) + (lr2 + lr3);

    // ---- fp32 combine of the two j-halves through LDS ----
    __shared__ float OB[4][64][20];
    __shared__ float LB[4][32];

    if (jh == 1) {
#pragma unroll
        for (int r4 = 0; r4 < 4; ++r4) {
            float4 v = {oacc[r4 * 4], oacc[r4 * 4 + 1], oacc[r4 * 4 + 2], oacc[r4 * 4 + 3]};
            *(float4*)&OB[wq][l][r4 * 4] = v;
        }
        float tu = lrun + __shfl_xor(lrun, 32);
        if (hi == 0) LB[wq][il] = tu;
    }
    __syncthreads();
    if (jh == 0) {
#pragma unroll
        for (int r = 0; r < 16; ++r) oacc[r] += OB[wq][l][r];
        float tl = lrun + __shfl_xor(lrun, 32);
        float inv = 1.f / (tl + LB[wq][il]);

        float* base = ao2 + ((size_t)(b * 256 + h * 32)) * 1024 + ibase + il;
#pragma unroll
        for (int r = 0; r < 16; ++r) {
            int d = (r & 3) + 8 * (r >> 2) + 4 * hi;
            base[(size_t)d * 1024] = oacc[r] * inv;
        }
    }
}

// ---------------------------------------------------------------------------
// K3: per-(b,c) sum/sumsq of ao2 rows (contiguous 1024 floats). 1 wave/row.
// ---------------------------------------------------------------------------
__global__ __launch_bounds__(64) void psum_k(const float* __restrict__ ao2,
                                             float* __restrict__ p1,
                                             float* __restrict__ p2) {
    int row = blockIdx.x;
    const float* base = ao2 + (size_t)row * 1024;
    int l = threadIdx.x;
    float s = 0.f, q = 0.f;
#pragma unroll
    for (int t = 0; t < 4; ++t) {
        float4 v = *(const float4*)(base + l * 4 + t * 256);
        s += v.x + v.y + v.z + v.w;
        q += v.x * v.x + v.y * v.y + v.z * v.z + v.w * v.w;
    }
#pragma unroll
    for (int o = 1; o < 64; o <<= 1) {
        s += __shfl_xor(s, o);
        q += __shfl_xor(q, o);
    }
    if (l == 0) { p1[row] = s; p2[row] = q; }
}

// ---------------------------------------------------------------------------
// K4: per-batch LayerNorm stats (light, r11)
// ---------------------------------------------------------------------------
__global__ __launch_bounds__(256) void stats_k(const float* __restrict__ p1,
                                               const float* __restrict__ p2,
                                               const float* __restrict__ wlp,
                                               const float* __restrict__ blp,
                                               float* __restrict__ stats) {
    int b = blockIdx.x, c = threadIdx.x;
    float s = p1[b * 256 + c];
    float q = p2[b * 256 + c];
    float w0 = wlp[c * 4], w1 = wlp[c * 4 + 1], w2 = wlp[c * 4 + 2], w3 = wlp[c * 4 + 3];
    float S1 = w0 + w1 + w2 + w3, S2 = w0 * w0 + w1 * w1 + w2 * w2 + w3 * w3;
    float bl = blp[c];
    float su = S1 * s + 4096.f * bl;
    float sq = S2 * q + 2.f * bl * S1 * s + 4096.f * bl * bl;
    __shared__ float rs_[256], rq_[256];
    rs_[c] = su; rq_[c] = sq;
    __syncthreads();
    for (int o = 128; o > 0; o >>= 1) {
        if (c < o) { rs_[c] += rs_[c + o]; rq_[c] += rq_[c + o]; }
        __syncthreads();
    }
    if (c == 0) {
        const float N = 1048576.f;
        float mu = rs_[0] / N;
        float var = rq_[0] / N - mu * mu;
        stats[b] = mu;
        stats[8 + b] = rsqrtf(var + 1e-5f);
    }
}

// ---------------------------------------------------------------------------
// K5: MFMA projection GEMM (r19 double-buffered chunk axis, verified neutral
// vs r11 — kept). Grid (b, mt, otile): linear%8 = b -> per-XCD locality.
// ---------------------------------------------------------------------------
__global__ __launch_bounds__(256) void proj_k(const float* __restrict__ ao2,
                                              const float* __restrict__ wp,
                                              const float* __restrict__ wlp,
                                              const float* __restrict__ blp,
                                              const float* __restrict__ gamma,
                                              const float* __restrict__ beta,
                                              const float* __restrict__ stats,
                                              float* __restrict__ y) {
    int b = blockIdx.x;
    int mt = blockIdx.y;
    int otile = blockIdx.z * 64;
    float mu = stats[b], rs = stats[8 + b];

    __shared__ short As[2][64][40];
    __shared__ short Bs[2][128][40];

    int t = threadIdx.x;
    int w = t >> 6, l = t & 63, g = l >> 4, li = l & 15;
    int oh = (w >> 1) * 32, mh = (w & 1) * 64;

    f32x4 zero = {0.f, 0.f, 0.f, 0.f};
    f32x4 acc[2][4];
#pragma unroll
    for (int og = 0; og < 2; ++og)
#pragma unroll
        for (int mg = 0; mg < 4; ++mg) acc[og][mg] = zero;

    int so = t >> 2, sc = (t & 3) * 8;
    int bc = t & 31, bm = (t >> 5) * 16;
    int p = t >> 7;
    int wbase = bm & 63;

    for (int kc = 0; kc < 256; kc += 64) {
#pragma unroll
        for (int half = 0; half < 2; ++half) {
            int kcc = kc + half * 32;
            const float* wrow = wp + (size_t)(otile + so) * 256 + kcc + sc;
#pragma unroll
            for (int j = 0; j < 8; ++j) As[half][so][sc + j] = f2b(wrow[j]);
            int c = kcc + bc;
            float Ac = gamma[c] * rs;
            float Dc = Ac * (blp[c] - mu) + beta[c];
            float w0 = Ac * wlp[c * 4 + p * 2 + 0];
            float w1 = Ac * wlp[c * 4 + p * 2 + 1];
            const float* arow = ao2 + ((size_t)(b * 256 + c)) * 1024 + mt * 32 + (wbase >> 1);
            float4 a0 = *(const float4*)arow;
            float4 a1 = *(const float4*)(arow + 4);
            float av[8] = {a0.x, a0.y, a0.z, a0.w, a1.x, a1.y, a1.z, a1.w};
#pragma unroll
            for (int k = 0; k < 8; ++k) {
                Bs[half][bm + 2 * k    ][bc] = f2b(w0 * av[k] + Dc);
                Bs[half][bm + 2 * k + 1][bc] = f2b(w1 * av[k] + Dc);
            }
        }
        __syncthreads();
#pragma unroll
        for (int half = 0; half < 2; ++half) {
            bf16x8 af[2], bf_[4];
#pragma unroll
            for (int og = 0; og < 2; ++og)
                af[og] = *(const bf16x8*)&As[half][oh + og * 16 + li][8 * g];
#pragma unroll
            for (int mg = 0; mg < 4; ++mg)
                bf_[mg] = *(const bf16x8*)&Bs[half][mh + mg * 16 + li][8 * g];
#pragma unroll
            for (int og = 0; og < 2; ++og)
#pragma unroll
                for (int mg = 0; mg < 4; ++mg)
                    acc[og][mg] = MFMA16(af[og], bf_[mg], acc[og][mg]);
        }
        __syncthreads();
    }

#pragma unroll
    for (int og = 0; og < 2; ++og) {
        int o = otile + oh + og * 16 + 4 * g;
#pragma unroll
        for (int mg = 0; mg < 4; ++mg) {
            int m = mt * 128 + mh + mg * 16 + li;
            float* yp = y + ((size_t)b * 256 + o) * 4096 + m;
#pragma unroll
            for (int r = 0; r < 4; ++r) yp[(size_t)r * 4096] = acc[og][mg][r];
        }
    }
}

extern "C" void kernel_launch(void* const* d_in, const int* in_sizes, int n_in,
                              void* d_out, int out_size, void* d_ws, size_t ws_size,
                              hipStream_t stream) {
    const float* x      = (const float*)d_in[0];
    const float* w_qkv  = (const float*)d_in[1];
    const float* w_lp   = (const float*)d_in[2];
    const float* b_lp   = (const float*)d_in[3];
    const float* gamma  = (const float*)d_in[4];
    const float* beta   = (const float*)d_in[5];
    const float* w_proj = (const float*)d_in[6];
    float* y = (float*)d_out;

    short* qt   = (short*)d_out;        // 2097152 shorts
    short* ktr  = qt + 2097152;
    short* vvr  = ktr + 2097152;
    short* xt   = vvr + 2097152;
    short* wbuf = xt + 2097152;

    float* ao2   = (float*)d_ws;        // 2097152 floats [b][c][n]
    float* p1    = ao2 + 2097152;       // 2048
    float* p2    = p1 + 2048;           // 2048
    float* stats = p2 + 2048;           // 16

    wconv_k<<<96, 256, 0, stream>>>(w_qkv, wbuf);
    xt_k<<<dim3(32, 8), 256, 0, stream>>>(x, xt);
    qkv_k<<<dim3(8, 8, 12), 256, 0, stream>>>(wbuf, xt, qt, ktr, vvr);
    attn_k<<<dim3(64, 8), 512, 0, stream>>>(qt, ktr, vvr, ao2);
    psum_k<<<2048, 64, 0, stream>>>(ao2, p1, p2);
    stats_k<<<8, 256, 0, stream>>>(p1, p2, w_lp, b_lp, stats);
    proj_k<<<dim3(8, 32, 4), 256, 0, stream>>>(ao2, w_proj, w_lp, b_lp, gamma, beta, stats, y);
}

// Round 21
// 78.609 us; speedup vs baseline: 1.0189x; 1.0189x over previous
//
#include <hip/hip_runtime.h>
#include <hip/hip_bf16.h>

// attention scale folded with log2(e): softmax exp(x) = exp2(x * log2e)
#define ATT_SCALE_L2E 0.2550322540f   // 32^-0.5 * log2(e)

typedef __attribute__((ext_vector_type(8))) short bf16x8;
typedef __attribute__((ext_vector_type(4))) short bf16x4;
typedef __attribute__((ext_vector_type(4))) float f32x4;
typedef __attribute__((ext_vector_type(16))) float f32x16;
typedef __attribute__((ext_vector_type(4))) int i32x4;

#define MFMA16(a, b, c) __builtin_amdgcn_mfma_f32_16x16x32_bf16(a, b, c, 0, 0, 0)
#define MFMA32(a, b, c) __builtin_amdgcn_mfma_f32_32x32x16_bf16(a, b, c, 0, 0, 0)

__device__ inline short f2b(float f) {
    return __builtin_bit_cast(short, __float2bfloat16(f));
}

// packed f32x2 -> bf16x2 in one instruction
__device__ inline int cvt_pk(float a, float b) {
    int r;
    asm("v_cvt_pk_bf16_f32 %0, %1, %2" : "=v"(r) : "v"(a), "v"(b));
    return r;
}

// ---------------------------------------------------------------------------
// K0a: w_qkv fp32 -> bf16
// ---------------------------------------------------------------------------
__global__ __launch_bounds__(256) void wconv_k(const float* __restrict__ w,
                                               short* __restrict__ wb) {
    int i0 = (blockIdx.x * 256 + threadIdx.x) * 8;
    float4 lo = *(const float4*)(w + i0);
    float4 hi = *(const float4*)(w + i0 + 4);
    bf16x8 o;
    o[0] = f2b(lo.x); o[1] = f2b(lo.y); o[2] = f2b(lo.z); o[3] = f2b(lo.w);
    o[4] = f2b(hi.x); o[5] = f2b(hi.y); o[6] = f2b(hi.z); o[7] = f2b(hi.w);
    *(bf16x8*)(wb + i0) = o;
}

// ---------------------------------------------------------------------------
// K0b: fused downsample + transpose + bf16: xt[b][n][c]
// ---------------------------------------------------------------------------
__global__ __launch_bounds__(256) void xt_k(const float* __restrict__ x,
                                            short* __restrict__ xt) {
    int b = blockIdx.y;
    int t = threadIdx.x;
    int n = blockIdx.x * 32 + (t >> 3);
    const float* xb = x + (size_t)b * 1048576 + (n >> 5) * 128 + (n & 31) * 2;
    short* dst = xt + ((size_t)b * 1024 + n) * 256;
#pragma unroll
    for (int it = 0; it < 4; ++it) {
        int c = (t & 7) * 8 + it * 64;
        bf16x8 o;
#pragma unroll
        for (int j = 0; j < 8; ++j) o[j] = f2b(xb[(size_t)(c + j) * 4096]);
        *(bf16x8*)(dst + c) = o;
    }
}

// ---------------------------------------------------------------------------
// K1: QKV MFMA GEMM (LDS-free main loop), epilogue transpose (r11, verified).
// ---------------------------------------------------------------------------
__global__ __launch_bounds__(256) void qkv_k(const short* __restrict__ wb,
                                             const short* __restrict__ xt,
                                             short* __restrict__ qt,
                                             short* __restrict__ ktr,
                                             short* __restrict__ vvr) {
    int b = blockIdx.x;
    int ntile = blockIdx.y * 128;
    int otile = blockIdx.z * 64;
    int t = threadIdx.x;
    int w = t >> 6, l = t & 63, g = l >> 4, li = l & 15;
    int oh = (w & 1) * 32, mh = (w >> 1) * 64;
    int o_base = otile + oh;
    int head = o_base / 96;
    int role = (o_base >> 5) % 3;  // 0=q 1=k 2=v
    size_t bh = (size_t)b * 8 + head;

    const short* arow = wb + (size_t)o_base * 256;
    const short* brow = xt + ((size_t)b * 1024 + ntile + mh) * 256;

    f32x4 zero = {0.f, 0.f, 0.f, 0.f};
    f32x4 acc[2][4];
#pragma unroll
    for (int og = 0; og < 2; ++og)
#pragma unroll
        for (int mg = 0; mg < 4; ++mg) acc[og][mg] = zero;

#pragma unroll
    for (int kc = 0; kc < 256; kc += 32) {
        bf16x8 af[2], bf_[4];
#pragma unroll
        for (int og = 0; og < 2; ++og)
            af[og] = *(const bf16x8*)(arow + (size_t)(og * 16 + li) * 256 + kc + 8 * g);
#pragma unroll
        for (int mg = 0; mg < 4; ++mg)
            bf_[mg] = *(const bf16x8*)(brow + (size_t)(mg * 16 + li) * 256 + kc + 8 * g);
#pragma unroll
        for (int og = 0; og < 2; ++og)
#pragma unroll
            for (int mg = 0; mg < 4; ++mg)
                acc[og][mg] = MFMA16(af[og], bf_[mg], acc[og][mg]);
    }

    __shared__ short Tl[4][32][64];
    short (*Tw)[64] = Tl[w];
    float sc = (role == 0) ? ATT_SCALE_L2E : 1.f;

#pragma unroll
    for (int og = 0; og < 2; ++og)
#pragma unroll
        for (int mg = 0; mg < 4; ++mg)
#pragma unroll
            for (int r = 0; r < 4; ++r) {
                int op = og * 16 + 4 * g + r;
                int qp = (op >> 3) & 3;
                Tw[op][(mg * 16 + li) ^ (qp << 4)] = f2b(acc[og][mg][r] * sc);
            }
    __syncthreads();

    if (role == 0) {
#pragma unroll
        for (int it = 0; it < 4; ++it) {
            int s = it * 64 + l;
            int dq = (l & 3) * 8;
            int n = s >> 2;
            int q2 = dq >> 3;
            bf16x8 vo;
#pragma unroll
            for (int j = 0; j < 8; ++j)
                vo[j] = Tw[dq + j][n ^ (q2 << 4)];
            *(bf16x8*)(qt + ((size_t)bh * 1024 + ntile + mh + n) * 32 + dq) = vo;
        }
    } else if (role == 1) {
        int base_jb = (ntile + mh) >> 5;
#pragma unroll
        for (int it = 0; it < 4; ++it) {
            int s = it * 64 + l;
            int il2 = s & 31;
            int combo = (s >> 5) & 3;
            int jbr = s >> 7;
            int dq = combo * 8;
            int n_rel = jbr * 32 + il2;
            bf16x8 vo;
#pragma unroll
            for (int j = 0; j < 8; ++j)
                vo[j] = Tw[dq + j][n_rel ^ (combo << 4)];
            *(bf16x8*)(ktr + (size_t)bh * 32768 +
                       (size_t)(base_jb + jbr) * 1024 + combo * 256 + il2 * 8) = vo;
        }
    } else {
        int base_jb = (ntile + mh) >> 5;
#pragma unroll
        for (int it = 0; it < 4; ++it) {
            int s = it * 64 + l;
            int il2 = s & 31;
            int combo = (s >> 5) & 3;
            int jbr = s >> 7;
            int pan = combo >> 1, hi2 = combo & 1;
            int q2 = (il2 >> 3) & 3;
            int bn = jbr * 32 + pan * 16 + 4 * hi2;
            bf16x8 vo;
#pragma unroll
            for (int j = 0; j < 4; ++j) vo[j] = Tw[il2][(bn + j) ^ (q2 << 4)];
#pragma unroll
            for (int j = 0; j < 4; ++j) vo[4 + j] = Tw[il2][(bn + 8 + j) ^ (q2 << 4)];
            *(bf16x8*)(vvr + (size_t)bh * 32768 +
                       (size_t)(base_jb + jbr) * 1024 + combo * 256 + il2 * 8) = vo;
        }
    }
}

// ---------------------------------------------------------------------------
// K2: attention, swapped-QK^T 32x32 MFMA, P lane-local via rho-map (verified
// r5). Dense panel loads (16B/lane). In-block split-j: 8 waves, wave w =
// (i-chunk w&3, j-half w>>2); fp32 combine through LDS (exact). Grid
// (bh, itile): linear%8 = h -> per-XCD K/V locality. Output ao2[b][c][n].
// ---------------------------------------------------------------------------
__global__ __launch_bounds__(512) void attn_k(const short* __restrict__ qt,
                                              const short* __restrict__ ktr,
                                              const short* __restrict__ vvr,
                                              float* __restrict__ ao2) {
    int bh = blockIdx.x;
    int b = bh >> 3, h = bh & 7;
    int t = threadIdx.x;
    int w = t >> 6, l = t & 63;
    int il = l & 31, hi = l >> 5;
    int wq = w & 3, jh = w >> 2;
    int ibase = blockIdx.y * 128 + wq * 32;

    const short* qtb = qt + (size_t)bh * 32768;
    const short* kbase = ktr + (size_t)bh * 32768 + jh * 16384 + hi * 256 + il * 8;
    const short* vbase = vvr + (size_t)bh * 32768 + jh * 16384 + hi * 256 + il * 8;

    bf16x8 qf0 = *(const bf16x8*)(qtb + (size_t)(ibase + il) * 32 + 8 * hi);
    bf16x8 qf1 = *(const bf16x8*)(qtb + (size_t)(ibase + il) * 32 + 16 + 8 * hi);

    f32x16 zero16 = {0.f,0.f,0.f,0.f,0.f,0.f,0.f,0.f,0.f,0.f,0.f,0.f,0.f,0.f,0.f,0.f};
    f32x16 oacc = zero16;
    float lr0 = 0.f, lr1 = 0.f, lr2 = 0.f, lr3 = 0.f;

#pragma unroll 2
    for (int jb = 0; jb < 16; ++jb) {
        const short* kp = kbase + (size_t)jb * 1024;
        const short* vp = vbase + (size_t)jb * 1024;
        bf16x8 kf0 = *(const bf16x8*)(kp);
        bf16x8 kf1 = *(const bf16x8*)(kp + 512);
        f32x16 s = MFMA32(kf0, qf0, zero16);
        s = MFMA32(kf1, qf1, s);

        float p[16];
#pragma unroll
        for (int r = 0; r < 16; ++r) p[r] = exp2f(s[r]);
        lr0 += p[0] + p[4] + p[8]  + p[12];
        lr1 += p[1] + p[5] + p[9]  + p[13];
        lr2 += p[2] + p[6] + p[10] + p[14];
        lr3 += p[3] + p[7] + p[11] + p[15];

        i32x4 fa, fb;
        fa[0] = cvt_pk(p[0], p[1]);   fa[1] = cvt_pk(p[2], p[3]);
        fa[2] = cvt_pk(p[4], p[5]);   fa[3] = cvt_pk(p[6], p[7]);
        fb[0] = cvt_pk(p[8], p[9]);   fb[1] = cvt_pk(p[10], p[11]);
        fb[2] = cvt_pk(p[12], p[13]); fb[3] = cvt_pk(p[14], p[15]);
        bf16x8 pfa = __builtin_bit_cast(bf16x8, fa);
        bf16x8 pfb = __builtin_bit_cast(bf16x8, fb);

        bf16x8 vfa = *(const bf16x8*)(vp);
        bf16x8 vfb = *(const bf16x8*)(vp + 512);
        oacc = MFMA32(vfa, pfa, oacc);
        oacc = MFMA32(vfb, pfb, oacc);
    }

    float lrun = (lr0 + lr1) + (lr2 + lr3);

    // ---- fp32 combine of the two j-halves through LDS ----
    __shared__ float OB[4][64][20];
    __shared__ float LB[4][32];

    if (jh == 1) {
#pragma unroll
        for (int r4 = 0; r4 < 4; ++r4) {
            float4 v = {oacc[r4 * 4], oacc[r4 * 4 + 1], oacc[r4 * 4 + 2], oacc[r4 * 4 + 3]};
            *(float4*)&OB[wq][l][r4 * 4] = v;
        }
        float tu = lrun + __shfl_xor(lrun, 32);
        if (hi == 0) LB[wq][il] = tu;
    }
    __syncthreads();
    if (jh == 0) {
#pragma unroll
        for (int r = 0; r < 16; ++r) oacc[r] += OB[wq][l][r];
        float tl = lrun + __shfl_xor(lrun, 32);
        float inv = 1.f / (tl + LB[wq][il]);

        float* base = ao2 + ((size_t)(b * 256 + h * 32)) * 1024 + ibase + il;
#pragma unroll
        for (int r = 0; r < 16; ++r) {
            int d = (r & 3) + 8 * (r >> 2) + 4 * hi;
            base[(size_t)d * 1024] = oacc[r] * inv;
        }
    }
}

// ---------------------------------------------------------------------------
// K3: per-(b,c) sum/sumsq of ao2 rows (contiguous 1024 floats). 1 wave/row.
// ---------------------------------------------------------------------------
__global__ __launch_bounds__(64) void psum_k(const float* __restrict__ ao2,
                                             float* __restrict__ p1,
                                             float* __restrict__ p2) {
    int row = blockIdx.x;
    const float* base = ao2 + (size_t)row * 1024;
    int l = threadIdx.x;
    float s = 0.f, q = 0.f;
#pragma unroll
    for (int t = 0; t < 4; ++t) {
        float4 v = *(const float4*)(base + l * 4 + t * 256);
        s += v.x + v.y + v.z + v.w;
        q += v.x * v.x + v.y * v.y + v.z * v.z + v.w * v.w;
    }
#pragma unroll
    for (int o = 1; o < 64; o <<= 1) {
        s += __shfl_xor(s, o);
        q += __shfl_xor(q, o);
    }
    if (l == 0) { p1[row] = s; p2[row] = q; }
}

// ---------------------------------------------------------------------------
// K4: per-batch LayerNorm stats (light, r11)
// ---------------------------------------------------------------------------
__global__ __launch_bounds__(256) void stats_k(const float* __restrict__ p1,
                                               const float* __restrict__ p2,
                                               const float* __restrict__ wlp,
                                               const float* __restrict__ blp,
                                               float* __restrict__ stats) {
    int b = blockIdx.x, c = threadIdx.x;
    float s = p1[b * 256 + c];
    float q = p2[b * 256 + c];
    float w0 = wlp[c * 4], w1 = wlp[c * 4 + 1], w2 = wlp[c * 4 + 2], w3 = wlp[c * 4 + 3];
    float S1 = w0 + w1 + w2 + w3, S2 = w0 * w0 + w1 * w1 + w2 * w2 + w3 * w3;
    float bl = blp[c];
    float su = S1 * s + 4096.f * bl;
    float sq = S2 * q + 2.f * bl * S1 * s + 4096.f * bl * bl;
    __shared__ float rs_[256], rq_[256];
    rs_[c] = su; rq_[c] = sq;
    __syncthreads();
    for (int o = 128; o > 0; o >>= 1) {
        if (c < o) { rs_[c] += rs_[c + o]; rq_[c] += rq_[c + o]; }
        __syncthreads();
    }
    if (c == 0) {
        const float N = 1048576.f;
        float mu = rs_[0] / N;
        float var = rq_[0] / N - mu * mu;
        stats[b] = mu;
        stats[8 + b] = rsqrtf(var + 1e-5f);
    }
}

// ---------------------------------------------------------------------------
// K5: MFMA projection GEMM with fused upsample+LayerNorm B-operand (r11 exact).
// Grid (b, mt, otile): linear%8 = b -> per-XCD ao2[b] locality.
// ---------------------------------------------------------------------------
__global__ __launch_bounds__(256) void proj_k(const float* __restrict__ ao2,
                                              const float* __restrict__ wp,
                                              const float* __restrict__ wlp,
                                              const float* __restrict__ blp,
                                              const float* __restrict__ gamma,
                                              const float* __restrict__ beta,
                                              const float* __restrict__ stats,
                                              float* __restrict__ y) {
    int b = blockIdx.x;
    int mt = blockIdx.y;
    int otile = blockIdx.z * 64;
    float mu = stats[b], rs = stats[8 + b];

    __shared__ short As[64][40];
    __shared__ short Bs[128][40];

    int t = threadIdx.x;
    int w = t >> 6, l = t & 63, g = l >> 4, li = l & 15;
    int oh = (w >> 1) * 32, mh = (w & 1) * 64;

    f32x4 zero = {0.f, 0.f, 0.f, 0.f};
    f32x4 acc[2][4];
#pragma unroll
    for (int og = 0; og < 2; ++og)
#pragma unroll
        for (int mg = 0; mg < 4; ++mg) acc[og][mg] = zero;

    int so = t >> 2, sc = (t & 3) * 8;
    int bc = t & 31, bm = (t >> 5) * 16;
    int p = t >> 7;
    int wbase = bm & 63;

    for (int kc = 0; kc < 256; kc += 32) {
        const float* wrow = wp + (size_t)(otile + so) * 256 + kc + sc;
#pragma unroll
        for (int j = 0; j < 8; ++j) As[so][sc + j] = f2b(wrow[j]);
        int c = kc + bc;
        float Ac = gamma[c] * rs;
        float Dc = Ac * (blp[c] - mu) + beta[c];
        float w0 = Ac * wlp[c * 4 + p * 2 + 0];
        float w1 = Ac * wlp[c * 4 + p * 2 + 1];
        const float* arow = ao2 + ((size_t)(b * 256 + c)) * 1024 + mt * 32 + (wbase >> 1);
        float4 a0 = *(const float4*)arow;
        float4 a1 = *(const float4*)(arow + 4);
        float av[8] = {a0.x, a0.y, a0.z, a0.w, a1.x, a1.y, a1.z, a1.w};
#pragma unroll
        for (int k = 0; k < 8; ++k) {
            Bs[bm + 2 * k    ][bc] = f2b(w0 * av[k] + Dc);
            Bs[bm + 2 * k + 1][bc] = f2b(w1 * av[k] + Dc);
        }
        __syncthreads();
        bf16x8 af[2], bf_[4];
#pragma unroll
        for (int og = 0; og < 2; ++og) af[og] = *(const bf16x8*)&As[oh + og * 16 + li][8 * g];
#pragma unroll
        for (int mg = 0; mg < 4; ++mg) bf_[mg] = *(const bf16x8*)&Bs[mh + mg * 16 + li][8 * g];
#pragma unroll
        for (int og = 0; og < 2; ++og)
#pragma unroll
            for (int mg = 0; mg < 4; ++mg) acc[og][mg] = MFMA16(af[og], bf_[mg], acc[og][mg]);
        __syncthreads();
    }

#pragma unroll
    for (int og = 0; og < 2; ++og) {
        int o = otile + oh + og * 16 + 4 * g;
#pragma unroll
        for (int mg = 0; mg < 4; ++mg) {
            int m = mt * 128 + mh + mg * 16 + li;
            float* yp = y + ((size_t)b * 256 + o) * 4096 + m;
#pragma unroll
            for (int r = 0; r < 4; ++r) yp[(size_t)r * 4096] = acc[og][mg][r];
        }
    }
}

extern "C" void kernel_launch(void* const* d_in, const int* in_sizes, int n_in,
                              void* d_out, int out_size, void* d_ws, size_t ws_size,
                              hipStream_t stream) {
    const float* x      = (const float*)d_in[0];
    const float* w_qkv  = (const float*)d_in[1];
    const float* w_lp   = (const float*)d_in[2];
    const float* b_lp   = (const float*)d_in[3];
    const float* gamma  = (const float*)d_in[4];
    const float* beta   = (const float*)d_in[5];
    const float* w_proj = (const float*)d_in[6];
    float* y = (float*)d_out;

    short* qt   = (short*)d_out;        // 2097152 shorts
    short* ktr  = qt + 2097152;
    short* vvr  = ktr + 2097152;
    short* xt   = vvr + 2097152;
    short* wbuf = xt + 2097152;

    float* ao2   = (float*)d_ws;        // 2097152 floats [b][c][n]
    float* p1    = ao2 + 2097152;       // 2048
    float* p2    = p1 + 2048;           // 2048
    float* stats = p2 + 2048;           // 16

    wconv_k<<<96, 256, 0, stream>>>(w_qkv, wbuf);
    xt_k<<<dim3(32, 8), 256, 0, stream>>>(x, xt);
    qkv_k<<<dim3(8, 8, 12), 256, 0, stream>>>(wbuf, xt, qt, ktr, vvr);
    attn_k<<<dim3(64, 8), 512, 0, stream>>>(qt, ktr, vvr, ao2);
    psum_k<<<2048, 64, 0, stream>>>(ao2, p1, p2);
    stats_k<<<8, 256, 0, stream>>>(p1, p2, w_lp, b_lp, stats);
    proj_k<<<dim3(8, 32, 4), 256, 0, stream>>>(ao2, w_proj, w_lp, b_lp, gamma, beta, stats, y);
}

// Round 22
// 74.444 us; speedup vs baseline: 1.0760x; 1.0559x over previous
//
#include <hip/hip_runtime.h>
#include <hip/hip_bf16.h>

// attention scale folded with log2(e): softmax exp(x) = exp2(x * log2e)
#define ATT_SCALE_L2E 0.2550322540f   // 32^-0.5 * log2(e)

typedef __attribute__((ext_vector_type(8))) short bf16x8;
typedef __attribute__((ext_vector_type(4))) short bf16x4;
typedef __attribute__((ext_vector_type(4))) float f32x4;
typedef __attribute__((ext_vector_type(16))) float f32x16;
typedef __attribute__((ext_vector_type(4))) int i32x4;

#define MFMA16(a, b, c) __builtin_amdgcn_mfma_f32_16x16x32_bf16(a, b, c, 0, 0, 0)
#define MFMA32(a, b, c) __builtin_amdgcn_mfma_f32_32x32x16_bf16(a, b, c, 0, 0, 0)

__device__ inline short f2b(float f) {
    return __builtin_bit_cast(short, __float2bfloat16(f));
}

// packed f32x2 -> bf16x2 in one instruction
__device__ inline int cvt_pk(float a, float b) {
    int r;
    asm("v_cvt_pk_bf16_f32 %0, %1, %2" : "=v"(r) : "v"(a), "v"(b));
    return r;
}

// ---------------------------------------------------------------------------
// K0: fused prep — blocks 0..95: w_qkv fp32->bf16 (wconv body);
//     blocks 96..351: downsample+transpose+bf16 xt[b][n][c] (xt body).
// Bodies byte-identical to the verified r11 kernels; only block-index
// mapping changes. Saves one kernel-launch boundary.
// ---------------------------------------------------------------------------
__global__ __launch_bounds__(256) void prep_k(const float* __restrict__ w,
                                              short* __restrict__ wb,
                                              const float* __restrict__ x,
                                              short* __restrict__ xt) {
    int bx = blockIdx.x;
    int t = threadIdx.x;
    if (bx < 96) {
        int i0 = (bx * 256 + t) * 8;
        float4 lo = *(const float4*)(w + i0);
        float4 hi = *(const float4*)(w + i0 + 4);
        bf16x8 o;
        o[0] = f2b(lo.x); o[1] = f2b(lo.y); o[2] = f2b(lo.z); o[3] = f2b(lo.w);
        o[4] = f2b(hi.x); o[5] = f2b(hi.y); o[6] = f2b(hi.z); o[7] = f2b(hi.w);
        *(bf16x8*)(wb + i0) = o;
    } else {
        int idx = bx - 96;              // 0..255
        int b = idx >> 5;               // 0..7   (was blockIdx.y)
        int xn = idx & 31;              // 0..31  (was blockIdx.x)
        int n = xn * 32 + (t >> 3);
        const float* xb = x + (size_t)b * 1048576 + (n >> 5) * 128 + (n & 31) * 2;
        short* dst = xt + ((size_t)b * 1024 + n) * 256;
#pragma unroll
        for (int it = 0; it < 4; ++it) {
            int c = (t & 7) * 8 + it * 64;
            bf16x8 o;
#pragma unroll
            for (int j = 0; j < 8; ++j) o[j] = f2b(xb[(size_t)(c + j) * 4096]);
            *(bf16x8*)(dst + c) = o;
        }
    }
}

// ---------------------------------------------------------------------------
// K1: QKV MFMA GEMM (LDS-free main loop), epilogue transpose (r11, verified).
// ---------------------------------------------------------------------------
__global__ __launch_bounds__(256) void qkv_k(const short* __restrict__ wb,
                                             const short* __restrict__ xt,
                                             short* __restrict__ qt,
                                             short* __restrict__ ktr,
                                             short* __restrict__ vvr) {
    int b = blockIdx.x;
    int ntile = blockIdx.y * 128;
    int otile = blockIdx.z * 64;
    int t = threadIdx.x;
    int w = t >> 6, l = t & 63, g = l >> 4, li = l & 15;
    int oh = (w & 1) * 32, mh = (w >> 1) * 64;
    int o_base = otile + oh;
    int head = o_base / 96;
    int role = (o_base >> 5) % 3;  // 0=q 1=k 2=v
    size_t bh = (size_t)b * 8 + head;

    const short* arow = wb + (size_t)o_base * 256;
    const short* brow = xt + ((size_t)b * 1024 + ntile + mh) * 256;

    f32x4 zero = {0.f, 0.f, 0.f, 0.f};
    f32x4 acc[2][4];
#pragma unroll
    for (int og = 0; og < 2; ++og)
#pragma unroll
        for (int mg = 0; mg < 4; ++mg) acc[og][mg] = zero;

#pragma unroll
    for (int kc = 0; kc < 256; kc += 32) {
        bf16x8 af[2], bf_[4];
#pragma unroll
        for (int og = 0; og < 2; ++og)
            af[og] = *(const bf16x8*)(arow + (size_t)(og * 16 + li) * 256 + kc + 8 * g);
#pragma unroll
        for (int mg = 0; mg < 4; ++mg)
            bf_[mg] = *(const bf16x8*)(brow + (size_t)(mg * 16 + li) * 256 + kc + 8 * g);
#pragma unroll
        for (int og = 0; og < 2; ++og)
#pragma unroll
            for (int mg = 0; mg < 4; ++mg)
                acc[og][mg] = MFMA16(af[og], bf_[mg], acc[og][mg]);
    }

    __shared__ short Tl[4][32][64];
    short (*Tw)[64] = Tl[w];
    float sc = (role == 0) ? ATT_SCALE_L2E : 1.f;

#pragma unroll
    for (int og = 0; og < 2; ++og)
#pragma unroll
        for (int mg = 0; mg < 4; ++mg)
#pragma unroll
            for (int r = 0; r < 4; ++r) {
                int op = og * 16 + 4 * g + r;
                int qp = (op >> 3) & 3;
                Tw[op][(mg * 16 + li) ^ (qp << 4)] = f2b(acc[og][mg][r] * sc);
            }
    __syncthreads();

    if (role == 0) {
#pragma unroll
        for (int it = 0; it < 4; ++it) {
            int s = it * 64 + l;
            int dq = (l & 3) * 8;
            int n = s >> 2;
            int q2 = dq >> 3;
            bf16x8 vo;
#pragma unroll
            for (int j = 0; j < 8; ++j)
                vo[j] = Tw[dq + j][n ^ (q2 << 4)];
            *(bf16x8*)(qt + ((size_t)bh * 1024 + ntile + mh + n) * 32 + dq) = vo;
        }
    } else if (role == 1) {
        int base_jb = (ntile + mh) >> 5;
#pragma unroll
        for (int it = 0; it < 4; ++it) {
            int s = it * 64 + l;
            int il2 = s & 31;
            int combo = (s >> 5) & 3;
            int jbr = s >> 7;
            int dq = combo * 8;
            int n_rel = jbr * 32 + il2;
            bf16x8 vo;
#pragma unroll
            for (int j = 0; j < 8; ++j)
                vo[j] = Tw[dq + j][n_rel ^ (combo << 4)];
            *(bf16x8*)(ktr + (size_t)bh * 32768 +
                       (size_t)(base_jb + jbr) * 1024 + combo * 256 + il2 * 8) = vo;
        }
    } else {
        int base_jb = (ntile + mh) >> 5;
#pragma unroll
        for (int it = 0; it < 4; ++it) {
            int s = it * 64 + l;
            int il2 = s & 31;
            int combo = (s >> 5) & 3;
            int jbr = s >> 7;
            int pan = combo >> 1, hi2 = combo & 1;
            int q2 = (il2 >> 3) & 3;
            int bn = jbr * 32 + pan * 16 + 4 * hi2;
            bf16x8 vo;
#pragma unroll
            for (int j = 0; j < 4; ++j) vo[j] = Tw[il2][(bn + j) ^ (q2 << 4)];
#pragma unroll
            for (int j = 0; j < 4; ++j) vo[4 + j] = Tw[il2][(bn + 8 + j) ^ (q2 << 4)];
            *(bf16x8*)(vvr + (size_t)bh * 32768 +
                       (size_t)(base_jb + jbr) * 1024 + combo * 256 + il2 * 8) = vo;
        }
    }
}

// ---------------------------------------------------------------------------
// K2: attention (r11, verified best). Output ao2[b][c][n].
// ---------------------------------------------------------------------------
__global__ __launch_bounds__(512) void attn_k(const short* __restrict__ qt,
                                              const short* __restrict__ ktr,
                                              const short* __restrict__ vvr,
                                              float* __restrict__ ao2) {
    int bh = blockIdx.x;
    int b = bh >> 3, h = bh & 7;
    int t = threadIdx.x;
    int w = t >> 6, l = t & 63;
    int il = l & 31, hi = l >> 5;
    int wq = w & 3, jh = w >> 2;
    int ibase = blockIdx.y * 128 + wq * 32;

    const short* qtb = qt + (size_t)bh * 32768;
    const short* kbase = ktr + (size_t)bh * 32768 + jh * 16384 + hi * 256 + il * 8;
    const short* vbase = vvr + (size_t)bh * 32768 + jh * 16384 + hi * 256 + il * 8;

    bf16x8 qf0 = *(const bf16x8*)(qtb + (size_t)(ibase + il) * 32 + 8 * hi);
    bf16x8 qf1 = *(const bf16x8*)(qtb + (size_t)(ibase + il) * 32 + 16 + 8 * hi);

    f32x16 zero16 = {0.f,0.f,0.f,0.f,0.f,0.f,0.f,0.f,0.f,0.f,0.f,0.f,0.f,0.f,0.f,0.f};
    f32x16 oacc = zero16;
    float lr0 = 0.f, lr1 = 0.f, lr2 = 0.f, lr3 = 0.f;

#pragma unroll 2
    for (int jb = 0; jb < 16; ++jb) {
        const short* kp = kbase + (size_t)jb * 1024;
        const short* vp = vbase + (size_t)jb * 1024;
        bf16x8 kf0 = *(const bf16x8*)(kp);
        bf16x8 kf1 = *(const bf16x8*)(kp + 512);
        f32x16 s = MFMA32(kf0, qf0, zero16);
        s = MFMA32(kf1, qf1, s);

        float p[16];
#pragma unroll
        for (int r = 0; r < 16; ++r) p[r] = exp2f(s[r]);
        lr0 += p[0] + p[4] + p[8]  + p[12];
        lr1 += p[1] + p[5] + p[9]  + p[13];
        lr2 += p[2] + p[6] + p[10] + p[14];
        lr3 += p[3] + p[7] + p[11] + p[15];

        i32x4 fa, fb;
        fa[0] = cvt_pk(p[0], p[1]);   fa[1] = cvt_pk(p[2], p[3]);
        fa[2] = cvt_pk(p[4], p[5]);   fa[3] = cvt_pk(p[6], p[7]);
        fb[0] = cvt_pk(p[8], p[9]);   fb[1] = cvt_pk(p[10], p[11]);
        fb[2] = cvt_pk(p[12], p[13]); fb[3] = cvt_pk(p[14], p[15]);
        bf16x8 pfa = __builtin_bit_cast(bf16x8, fa);
        bf16x8 pfb = __builtin_bit_cast(bf16x8, fb);

        bf16x8 vfa = *(const bf16x8*)(vp);
        bf16x8 vfb = *(const bf16x8*)(vp + 512);
        oacc = MFMA32(vfa, pfa, oacc);
        oacc = MFMA32(vfb, pfb, oacc);
    }

    float lrun = (lr0 + lr1) + (lr2 + lr3);

    // ---- fp32 combine of the two j-halves through LDS ----
    __shared__ float OB[4][64][20];
    __shared__ float LB[4][32];

    if (jh == 1) {
#pragma unroll
        for (int r4 = 0; r4 < 4; ++r4) {
            float4 v = {oacc[r4 * 4], oacc[r4 * 4 + 1], oacc[r4 * 4 + 2], oacc[r4 * 4 + 3]};
            *(float4*)&OB[wq][l][r4 * 4] = v;
        }
        float tu = lrun + __shfl_xor(lrun, 32);
        if (hi == 0) LB[wq][il] = tu;
    }
    __syncthreads();
    if (jh == 0) {
#pragma unroll
        for (int r = 0; r < 16; ++r) oacc[r] += OB[wq][l][r];
        float tl = lrun + __shfl_xor(lrun, 32);
        float inv = 1.f / (tl + LB[wq][il]);

        float* base = ao2 + ((size_t)(b * 256 + h * 32)) * 1024 + ibase + il;
#pragma unroll
        for (int r = 0; r < 16; ++r) {
            int d = (r & 3) + 8 * (r >> 2) + 4 * hi;
            base[(size_t)d * 1024] = oacc[r] * inv;
        }
    }
}

// ---------------------------------------------------------------------------
// K3: per-(b,c) sum/sumsq of ao2 rows (contiguous 1024 floats). 1 wave/row.
// ---------------------------------------------------------------------------
__global__ __launch_bounds__(64) void psum_k(const float* __restrict__ ao2,
                                             float* __restrict__ p1,
                                             float* __restrict__ p2) {
    int row = blockIdx.x;
    const float* base = ao2 + (size_t)row * 1024;
    int l = threadIdx.x;
    float s = 0.f, q = 0.f;
#pragma unroll
    for (int t = 0; t < 4; ++t) {
        float4 v = *(const float4*)(base + l * 4 + t * 256);
        s += v.x + v.y + v.z + v.w;
        q += v.x * v.x + v.y * v.y + v.z * v.z + v.w * v.w;
    }
#pragma unroll
    for (int o = 1; o < 64; o <<= 1) {
        s += __shfl_xor(s, o);
        q += __shfl_xor(q, o);
    }
    if (l == 0) { p1[row] = s; p2[row] = q; }
}

// ---------------------------------------------------------------------------
// K4: per-batch LayerNorm stats (light, r11)
// ---------------------------------------------------------------------------
__global__ __launch_bounds__(256) void stats_k(const float* __restrict__ p1,
                                               const float* __restrict__ p2,
                                               const float* __restrict__ wlp,
                                               const float* __restrict__ blp,
                                               float* __restrict__ stats) {
    int b = blockIdx.x, c = threadIdx.x;
    float s = p1[b * 256 + c];
    float q = p2[b * 256 + c];
    float w0 = wlp[c * 4], w1 = wlp[c * 4 + 1], w2 = wlp[c * 4 + 2], w3 = wlp[c * 4 + 3];
    float S1 = w0 + w1 + w2 + w3, S2 = w0 * w0 + w1 * w1 + w2 * w2 + w3 * w3;
    float bl = blp[c];
    float su = S1 * s + 4096.f * bl;
    float sq = S2 * q + 2.f * bl * S1 * s + 4096.f * bl * bl;
    __shared__ float rs_[256], rq_[256];
    rs_[c] = su; rq_[c] = sq;
    __syncthreads();
    for (int o = 128; o > 0; o >>= 1) {
        if (c < o) { rs_[c] += rs_[c + o]; rq_[c] += rq_[c + o]; }
        __syncthreads();
    }
    if (c == 0) {
        const float N = 1048576.f;
        float mu = rs_[0] / N;
        float var = rq_[0] / N - mu * mu;
        stats[b] = mu;
        stats[8 + b] = rsqrtf(var + 1e-5f);
    }
}

// ---------------------------------------------------------------------------
// K5: MFMA projection GEMM with fused upsample+LayerNorm B-operand (r11 exact).
// Grid (b, mt, otile): linear%8 = b -> per-XCD ao2[b] locality.
// ---------------------------------------------------------------------------
__global__ __launch_bounds__(256) void proj_k(const float* __restrict__ ao2,
                                              const float* __restrict__ wp,
                                              const float* __restrict__ wlp,
                                              const float* __restrict__ blp,
                                              const float* __restrict__ gamma,
                                              const float* __restrict__ beta,
                                              const float* __restrict__ stats,
                                              float* __restrict__ y) {
    int b = blockIdx.x;
    int mt = blockIdx.y;
    int otile = blockIdx.z * 64;
    float mu = stats[b], rs = stats[8 + b];

    __shared__ short As[64][40];
    __shared__ short Bs[128][40];

    int t = threadIdx.x;
    int w = t >> 6, l = t & 63, g = l >> 4, li = l & 15;
    int oh = (w >> 1) * 32, mh = (w & 1) * 64;

    f32x4 zero = {0.f, 0.f, 0.f, 0.f};
    f32x4 acc[2][4];
#pragma unroll
    for (int og = 0; og < 2; ++og)
#pragma unroll
        for (int mg = 0; mg < 4; ++mg) acc[og][mg] = zero;

    int so = t >> 2, sc = (t & 3) * 8;
    int bc = t & 31, bm = (t >> 5) * 16;
    int p = t >> 7;
    int wbase = bm & 63;

    for (int kc = 0; kc < 256; kc += 32) {
        const float* wrow = wp + (size_t)(otile + so) * 256 + kc + sc;
#pragma unroll
        for (int j = 0; j < 8; ++j) As[so][sc + j] = f2b(wrow[j]);
        int c = kc + bc;
        float Ac = gamma[c] * rs;
        float Dc = Ac * (blp[c] - mu) + beta[c];
        float w0 = Ac * wlp[c * 4 + p * 2 + 0];
        float w1 = Ac * wlp[c * 4 + p * 2 + 1];
        const float* arow = ao2 + ((size_t)(b * 256 + c)) * 1024 + mt * 32 + (wbase >> 1);
        float4 a0 = *(const float4*)arow;
        float4 a1 = *(const float4*)(arow + 4);
        float av[8] = {a0.x, a0.y, a0.z, a0.w, a1.x, a1.y, a1.z, a1.w};
#pragma unroll
        for (int k = 0; k < 8; ++k) {
            Bs[bm + 2 * k    ][bc] = f2b(w0 * av[k] + Dc);
            Bs[bm + 2 * k + 1][bc] = f2b(w1 * av[k] + Dc);
        }
        __syncthreads();
        bf16x8 af[2], bf_[4];
#pragma unroll
        for (int og = 0; og < 2; ++og) af[og] = *(const bf16x8*)&As[oh + og * 16 + li][8 * g];
#pragma unroll
        for (int mg = 0; mg < 4; ++mg) bf_[mg] = *(const bf16x8*)&Bs[mh + mg * 16 + li][8 * g];
#pragma unroll
        for (int og = 0; og < 2; ++og)
#pragma unroll
            for (int mg = 0; mg < 4; ++mg) acc[og][mg] = MFMA16(af[og], bf_[mg], acc[og][mg]);
        __syncthreads();
    }

#pragma unroll
    for (int og = 0; og < 2; ++og) {
        int o = otile + oh + og * 16 + 4 * g;
#pragma unroll
        for (int mg = 0; mg < 4; ++mg) {
            int m = mt * 128 + mh + mg * 16 + li;
            float* yp = y + ((size_t)b * 256 + o) * 4096 + m;
#pragma unroll
            for (int r = 0; r < 4; ++r) yp[(size_t)r * 4096] = acc[og][mg][r];
        }
    }
}

extern "C" void kernel_launch(void* const* d_in, const int* in_sizes, int n_in,
                              void* d_out, int out_size, void* d_ws, size_t ws_size,
                              hipStream_t stream) {
    const float* x      = (const float*)d_in[0];
    const float* w_qkv  = (const float*)d_in[1];
    const float* w_lp   = (const float*)d_in[2];
    const float* b_lp   = (const float*)d_in[3];
    const float* gamma  = (const float*)d_in[4];
    const float* beta   = (const float*)d_in[5];
    const float* w_proj = (const float*)d_in[6];
    float* y = (float*)d_out;

    short* qt   = (short*)d_out;        // 2097152 shorts
    short* ktr  = qt + 2097152;
    short* vvr  = ktr + 2097152;
    short* xt   = vvr + 2097152;
    short* wbuf = xt + 2097152;

    float* ao2   = (float*)d_ws;        // 2097152 floats [b][c][n]
    float* p1    = ao2 + 2097152;       // 2048
    float* p2    = p1 + 2048;           // 2048
    float* stats = p2 + 2048;           // 16

    prep_k<<<352, 256, 0, stream>>>(w_qkv, wbuf, x, xt);
    qkv_k<<<dim3(8, 8, 12), 256, 0, stream>>>(wbuf, xt, qt, ktr, vvr);
    attn_k<<<dim3(64, 8), 512, 0, stream>>>(qt, ktr, vvr, ao2);
    psum_k<<<2048, 64, 0, stream>>>(ao2, p1, p2);
    stats_k<<<8, 256, 0, stream>>>(p1, p2, w_lp, b_lp, stats);
    proj_k<<<dim3(8, 32, 4), 256, 0, stream>>>(ao2, w_proj, w_lp, b_lp, gamma, beta, stats, y);
}

// Round 23
// 73.103 us; speedup vs baseline: 1.0957x; 1.0184x over previous
//
#include <hip/hip_runtime.h>
#include <hip/hip_bf16.h>

// attention scale folded with log2(e): softmax exp(x) = exp2(x * log2e)
#define ATT_SCALE_L2E 0.2550322540f   // 32^-0.5 * log2(e)

typedef __attribute__((ext_vector_type(8))) short bf16x8;
typedef __attribute__((ext_vector_type(4))) short bf16x4;
typedef __attribute__((ext_vector_type(4))) float f32x4;
typedef __attribute__((ext_vector_type(16))) float f32x16;
typedef __attribute__((ext_vector_type(4))) int i32x4;

#define MFMA16(a, b, c) __builtin_amdgcn_mfma_f32_16x16x32_bf16(a, b, c, 0, 0, 0)
#define MFMA32(a, b, c) __builtin_amdgcn_mfma_f32_32x32x16_bf16(a, b, c, 0, 0, 0)

__device__ inline short f2b(float f) {
    return __builtin_bit_cast(short, __float2bfloat16(f));
}

// packed f32x2 -> bf16x2 in one instruction
__device__ inline int cvt_pk(float a, float b) {
    int r;
    asm("v_cvt_pk_bf16_f32 %0, %1, %2" : "=v"(r) : "v"(a), "v"(b));
    return r;
}

// ---------------------------------------------------------------------------
// K0: fused prep — blocks 0..95: w_qkv fp32->bf16 (wconv body);
//     blocks 96..351: downsample+transpose+bf16 xt[b][n][c] (xt body).
// (r22, verified: 78.6 -> 74.4 via launch fusion + overlap)
// ---------------------------------------------------------------------------
__global__ __launch_bounds__(256) void prep_k(const float* __restrict__ w,
                                              short* __restrict__ wb,
                                              const float* __restrict__ x,
                                              short* __restrict__ xt) {
    int bx = blockIdx.x;
    int t = threadIdx.x;
    if (bx < 96) {
        int i0 = (bx * 256 + t) * 8;
        float4 lo = *(const float4*)(w + i0);
        float4 hi = *(const float4*)(w + i0 + 4);
        bf16x8 o;
        o[0] = f2b(lo.x); o[1] = f2b(lo.y); o[2] = f2b(lo.z); o[3] = f2b(lo.w);
        o[4] = f2b(hi.x); o[5] = f2b(hi.y); o[6] = f2b(hi.z); o[7] = f2b(hi.w);
        *(bf16x8*)(wb + i0) = o;
    } else {
        int idx = bx - 96;              // 0..255
        int b = idx >> 5;               // 0..7
        int xn = idx & 31;              // 0..31
        int n = xn * 32 + (t >> 3);
        const float* xb = x + (size_t)b * 1048576 + (n >> 5) * 128 + (n & 31) * 2;
        short* dst = xt + ((size_t)b * 1024 + n) * 256;
#pragma unroll
        for (int it = 0; it < 4; ++it) {
            int c = (t & 7) * 8 + it * 64;
            bf16x8 o;
#pragma unroll
            for (int j = 0; j < 8; ++j) o[j] = f2b(xb[(size_t)(c + j) * 4096]);
            *(bf16x8*)(dst + c) = o;
        }
    }
}

// ---------------------------------------------------------------------------
// K1: QKV MFMA GEMM (LDS-free main loop), epilogue transpose (r11, verified).
// ---------------------------------------------------------------------------
__global__ __launch_bounds__(256) void qkv_k(const short* __restrict__ wb,
                                             const short* __restrict__ xt,
                                             short* __restrict__ qt,
                                             short* __restrict__ ktr,
                                             short* __restrict__ vvr) {
    int b = blockIdx.x;
    int ntile = blockIdx.y * 128;
    int otile = blockIdx.z * 64;
    int t = threadIdx.x;
    int w = t >> 6, l = t & 63, g = l >> 4, li = l & 15;
    int oh = (w & 1) * 32, mh = (w >> 1) * 64;
    int o_base = otile + oh;
    int head = o_base / 96;
    int role = (o_base >> 5) % 3;  // 0=q 1=k 2=v
    size_t bh = (size_t)b * 8 + head;

    const short* arow = wb + (size_t)o_base * 256;
    const short* brow = xt + ((size_t)b * 1024 + ntile + mh) * 256;

    f32x4 zero = {0.f, 0.f, 0.f, 0.f};
    f32x4 acc[2][4];
#pragma unroll
    for (int og = 0; og < 2; ++og)
#pragma unroll
        for (int mg = 0; mg < 4; ++mg) acc[og][mg] = zero;

#pragma unroll
    for (int kc = 0; kc < 256; kc += 32) {
        bf16x8 af[2], bf_[4];
#pragma unroll
        for (int og = 0; og < 2; ++og)
            af[og] = *(const bf16x8*)(arow + (size_t)(og * 16 + li) * 256 + kc + 8 * g);
#pragma unroll
        for (int mg = 0; mg < 4; ++mg)
            bf_[mg] = *(const bf16x8*)(brow + (size_t)(mg * 16 + li) * 256 + kc + 8 * g);
#pragma unroll
        for (int og = 0; og < 2; ++og)
#pragma unroll
            for (int mg = 0; mg < 4; ++mg)
                acc[og][mg] = MFMA16(af[og], bf_[mg], acc[og][mg]);
    }

    __shared__ short Tl[4][32][64];
    short (*Tw)[64] = Tl[w];
    float sc = (role == 0) ? ATT_SCALE_L2E : 1.f;

#pragma unroll
    for (int og = 0; og < 2; ++og)
#pragma unroll
        for (int mg = 0; mg < 4; ++mg)
#pragma unroll
            for (int r = 0; r < 4; ++r) {
                int op = og * 16 + 4 * g + r;
                int qp = (op >> 3) & 3;
                Tw[op][(mg * 16 + li) ^ (qp << 4)] = f2b(acc[og][mg][r] * sc);
            }
    __syncthreads();

    if (role == 0) {
#pragma unroll
        for (int it = 0; it < 4; ++it) {
            int s = it * 64 + l;
            int dq = (l & 3) * 8;
            int n = s >> 2;
            int q2 = dq >> 3;
            bf16x8 vo;
#pragma unroll
            for (int j = 0; j < 8; ++j)
                vo[j] = Tw[dq + j][n ^ (q2 << 4)];
            *(bf16x8*)(qt + ((size_t)bh * 1024 + ntile + mh + n) * 32 + dq) = vo;
        }
    } else if (role == 1) {
        int base_jb = (ntile + mh) >> 5;
#pragma unroll
        for (int it = 0; it < 4; ++it) {
            int s = it * 64 + l;
            int il2 = s & 31;
            int combo = (s >> 5) & 3;
            int jbr = s >> 7;
            int dq = combo * 8;
            int n_rel = jbr * 32 + il2;
            bf16x8 vo;
#pragma unroll
            for (int j = 0; j < 8; ++j)
                vo[j] = Tw[dq + j][n_rel ^ (combo << 4)];
            *(bf16x8*)(ktr + (size_t)bh * 32768 +
                       (size_t)(base_jb + jbr) * 1024 + combo * 256 + il2 * 8) = vo;
        }
    } else {
        int base_jb = (ntile + mh) >> 5;
#pragma unroll
        for (int it = 0; it < 4; ++it) {
            int s = it * 64 + l;
            int il2 = s & 31;
            int combo = (s >> 5) & 3;
            int jbr = s >> 7;
            int pan = combo >> 1, hi2 = combo & 1;
            int q2 = (il2 >> 3) & 3;
            int bn = jbr * 32 + pan * 16 + 4 * hi2;
            bf16x8 vo;
#pragma unroll
            for (int j = 0; j < 4; ++j) vo[j] = Tw[il2][(bn + j) ^ (q2 << 4)];
#pragma unroll
            for (int j = 0; j < 4; ++j) vo[4 + j] = Tw[il2][(bn + 8 + j) ^ (q2 << 4)];
            *(bf16x8*)(vvr + (size_t)bh * 32768 +
                       (size_t)(base_jb + jbr) * 1024 + combo * 256 + il2 * 8) = vo;
        }
    }
}

// ---------------------------------------------------------------------------
// K2: attention (r11, verified best). Output ao2[b][c][n].
// ---------------------------------------------------------------------------
__global__ __launch_bounds__(512) void attn_k(const short* __restrict__ qt,
                                              const short* __restrict__ ktr,
                                              const short* __restrict__ vvr,
                                              float* __restrict__ ao2) {
    int bh = blockIdx.x;
    int b = bh >> 3, h = bh & 7;
    int t = threadIdx.x;
    int w = t >> 6, l = t & 63;
    int il = l & 31, hi = l >> 5;
    int wq = w & 3, jh = w >> 2;
    int ibase = blockIdx.y * 128 + wq * 32;

    const short* qtb = qt + (size_t)bh * 32768;
    const short* kbase = ktr + (size_t)bh * 32768 + jh * 16384 + hi * 256 + il * 8;
    const short* vbase = vvr + (size_t)bh * 32768 + jh * 16384 + hi * 256 + il * 8;

    bf16x8 qf0 = *(const bf16x8*)(qtb + (size_t)(ibase + il) * 32 + 8 * hi);
    bf16x8 qf1 = *(const bf16x8*)(qtb + (size_t)(ibase + il) * 32 + 16 + 8 * hi);

    f32x16 zero16 = {0.f,0.f,0.f,0.f,0.f,0.f,0.f,0.f,0.f,0.f,0.f,0.f,0.f,0.f,0.f,0.f};
    f32x16 oacc = zero16;
    float lr0 = 0.f, lr1 = 0.f, lr2 = 0.f, lr3 = 0.f;

#pragma unroll 2
    for (int jb = 0; jb < 16; ++jb) {
        const short* kp = kbase + (size_t)jb * 1024;
        const short* vp = vbase + (size_t)jb * 1024;
        bf16x8 kf0 = *(const bf16x8*)(kp);
        bf16x8 kf1 = *(const bf16x8*)(kp + 512);
        f32x16 s = MFMA32(kf0, qf0, zero16);
        s = MFMA32(kf1, qf1, s);

        float p[16];
#pragma unroll
        for (int r = 0; r < 16; ++r) p[r] = exp2f(s[r]);
        lr0 += p[0] + p[4] + p[8]  + p[12];
        lr1 += p[1] + p[5] + p[9]  + p[13];
        lr2 += p[2] + p[6] + p[10] + p[14];
        lr3 += p[3] + p[7] + p[11] + p[15];

        i32x4 fa, fb;
        fa[0] = cvt_pk(p[0], p[1]);   fa[1] = cvt_pk(p[2], p[3]);
        fa[2] = cvt_pk(p[4], p[5]);   fa[3] = cvt_pk(p[6], p[7]);
        fb[0] = cvt_pk(p[8], p[9]);   fb[1] = cvt_pk(p[10], p[11]);
        fb[2] = cvt_pk(p[12], p[13]); fb[3] = cvt_pk(p[14], p[15]);
        bf16x8 pfa = __builtin_bit_cast(bf16x8, fa);
        bf16x8 pfb = __builtin_bit_cast(bf16x8, fb);

        bf16x8 vfa = *(const bf16x8*)(vp);
        bf16x8 vfb = *(const bf16x8*)(vp + 512);
        oacc = MFMA32(vfa, pfa, oacc);
        oacc = MFMA32(vfb, pfb, oacc);
    }

    float lrun = (lr0 + lr1) + (lr2 + lr3);

    // ---- fp32 combine of the two j-halves through LDS ----
    __shared__ float OB[4][64][20];
    __shared__ float LB[4][32];

    if (jh == 1) {
#pragma unroll
        for (int r4 = 0; r4 < 4; ++r4) {
            float4 v = {oacc[r4 * 4], oacc[r4 * 4 + 1], oacc[r4 * 4 + 2], oacc[r4 * 4 + 3]};
            *(float4*)&OB[wq][l][r4 * 4] = v;
        }
        float tu = lrun + __shfl_xor(lrun, 32);
        if (hi == 0) LB[wq][il] = tu;
    }
    __syncthreads();
    if (jh == 0) {
#pragma unroll
        for (int r = 0; r < 16; ++r) oacc[r] += OB[wq][l][r];
        float tl = lrun + __shfl_xor(lrun, 32);
        float inv = 1.f / (tl + LB[wq][il]);

        float* base = ao2 + ((size_t)(b * 256 + h * 32)) * 1024 + ibase + il;
#pragma unroll
        for (int r = 0; r < 16; ++r) {
            int d = (r & 3) + 8 * (r >> 2) + 4 * hi;
            base[(size_t)d * 1024] = oacc[r] * inv;
        }
    }
}

// ---------------------------------------------------------------------------
// K3: per-(b,c) sum/sumsq of ao2 rows (contiguous 1024 floats). 1 wave/row.
// ---------------------------------------------------------------------------
__global__ __launch_bounds__(64) void psum_k(const float* __restrict__ ao2,
                                             float* __restrict__ p1,
                                             float* __restrict__ p2) {
    int row = blockIdx.x;
    const float* base = ao2 + (size_t)row * 1024;
    int l = threadIdx.x;
    float s = 0.f, q = 0.f;
#pragma unroll
    for (int t = 0; t < 4; ++t) {
        float4 v = *(const float4*)(base + l * 4 + t * 256);
        s += v.x + v.y + v.z + v.w;
        q += v.x * v.x + v.y * v.y + v.z * v.z + v.w * v.w;
    }
#pragma unroll
    for (int o = 1; o < 64; o <<= 1) {
        s += __shfl_xor(s, o);
        q += __shfl_xor(q, o);
    }
    if (l == 0) { p1[row] = s; p2[row] = q; }
}

// ---------------------------------------------------------------------------
// K5: MFMA projection GEMM (r11 body) with the verified stats_k body inlined
// as a per-block prologue (each block redundantly computes its batch's mu/rs
// from p1/p2 — 512 L2-hot loads + LDS tree, deterministic, bit-identical per
// batch). Removes the stats_k launch + boundary.
// Grid (b, mt, otile): linear%8 = b -> per-XCD ao2[b] locality.
// ---------------------------------------------------------------------------
__global__ __launch_bounds__(256) void proj_k(const float* __restrict__ ao2,
                                              const float* __restrict__ wp,
                                              const float* __restrict__ wlp,
                                              const float* __restrict__ blp,
                                              const float* __restrict__ gamma,
                                              const float* __restrict__ beta,
                                              const float* __restrict__ p1,
                                              const float* __restrict__ p2,
                                              float* __restrict__ y) {
    int b = blockIdx.x;
    int mt = blockIdx.y;
    int otile = blockIdx.z * 64;
    int t = threadIdx.x;

    // ---- stats prologue (verbatim stats_k body; outputs via shared mss) ----
    __shared__ float red1[256], red2[256];
    __shared__ float mss[2];
    {
        int c = t;
        float s = p1[b * 256 + c];
        float q = p2[b * 256 + c];
        float u0 = wlp[c * 4], u1 = wlp[c * 4 + 1], u2 = wlp[c * 4 + 2], u3 = wlp[c * 4 + 3];
        float S1 = u0 + u1 + u2 + u3, S2 = u0 * u0 + u1 * u1 + u2 * u2 + u3 * u3;
        float bl = blp[c];
        red1[c] = S1 * s + 4096.f * bl;
        red2[c] = S2 * q + 2.f * bl * S1 * s + 4096.f * bl * bl;
        __syncthreads();
        for (int o = 128; o > 0; o >>= 1) {
            if (c < o) { red1[c] += red1[c + o]; red2[c] += red2[c + o]; }
            __syncthreads();
        }
        if (c == 0) {
            const float N = 1048576.f;
            float mu = red1[0] / N;
            float var = red2[0] / N - mu * mu;
            mss[0] = mu;
            mss[1] = rsqrtf(var + 1e-5f);
        }
        __syncthreads();
    }
    float mu = mss[0], rs = mss[1];

    __shared__ short As[64][40];
    __shared__ short Bs[128][40];

    int w = t >> 6, l = t & 63, g = l >> 4, li = l & 15;
    int oh = (w >> 1) * 32, mh = (w & 1) * 64;

    f32x4 zero = {0.f, 0.f, 0.f, 0.f};
    f32x4 acc[2][4];
#pragma unroll
    for (int og = 0; og < 2; ++og)
#pragma unroll
        for (int mg = 0; mg < 4; ++mg) acc[og][mg] = zero;

    int so = t >> 2, sc = (t & 3) * 8;
    int bc = t & 31, bm = (t >> 5) * 16;
    int p = t >> 7;
    int wbase = bm & 63;

    for (int kc = 0; kc < 256; kc += 32) {
        const float* wrow = wp + (size_t)(otile + so) * 256 + kc + sc;
#pragma unroll
        for (int j = 0; j < 8; ++j) As[so][sc + j] = f2b(wrow[j]);
        int c = kc + bc;
        float Ac = gamma[c] * rs;
        float Dc = Ac * (blp[c] - mu) + beta[c];
        float w0 = Ac * wlp[c * 4 + p * 2 + 0];
        float w1 = Ac * wlp[c * 4 + p * 2 + 1];
        const float* arow = ao2 + ((size_t)(b * 256 + c)) * 1024 + mt * 32 + (wbase >> 1);
        float4 a0 = *(const float4*)arow;
        float4 a1 = *(const float4*)(arow + 4);
        float av[8] = {a0.x, a0.y, a0.z, a0.w, a1.x, a1.y, a1.z, a1.w};
#pragma unroll
        for (int k = 0; k < 8; ++k) {
            Bs[bm + 2 * k    ][bc] = f2b(w0 * av[k] + Dc);
            Bs[bm + 2 * k + 1][bc] = f2b(w1 * av[k] + Dc);
        }
        __syncthreads();
        bf16x8 af[2], bf_[4];
#pragma unroll
        for (int og = 0; og < 2; ++og) af[og] = *(const bf16x8*)&As[oh + og * 16 + li][8 * g];
#pragma unroll
        for (int mg = 0; mg < 4; ++mg) bf_[mg] = *(const bf16x8*)&Bs[mh + mg * 16 + li][8 * g];
#pragma unroll
        for (int og = 0; og < 2; ++og)
#pragma unroll
            for (int mg = 0; mg < 4; ++mg) acc[og][mg] = MFMA16(af[og], bf_[mg], acc[og][mg]);
        __syncthreads();
    }

#pragma unroll
    for (int og = 0; og < 2; ++og) {
        int o = otile + oh + og * 16 + 4 * g;
#pragma unroll
        for (int mg = 0; mg < 4; ++mg) {
            int m = mt * 128 + mh + mg * 16 + li;
            float* yp = y + ((size_t)b * 256 + o) * 4096 + m;
#pragma unroll
            for (int r = 0; r < 4; ++r) yp[(size_t)r * 4096] = acc[og][mg][r];
        }
    }
}

extern "C" void kernel_launch(void* const* d_in, const int* in_sizes, int n_in,
                              void* d_out, int out_size, void* d_ws, size_t ws_size,
                              hipStream_t stream) {
    const float* x      = (const float*)d_in[0];
    const float* w_qkv  = (const float*)d_in[1];
    const float* w_lp   = (const float*)d_in[2];
    const float* b_lp   = (const float*)d_in[3];
    const float* gamma  = (const float*)d_in[4];
    const float* beta   = (const float*)d_in[5];
    const float* w_proj = (const float*)d_in[6];
    float* y = (float*)d_out;

    short* qt   = (short*)d_out;        // 2097152 shorts
    short* ktr  = qt + 2097152;
    short* vvr  = ktr + 2097152;
    short* xt   = vvr + 2097152;
    short* wbuf = xt + 2097152;

    float* ao2   = (float*)d_ws;        // 2097152 floats [b][c][n]
    float* p1    = ao2 + 2097152;       // 2048
    float* p2    = p1 + 2048;           // 2048

    prep_k<<<352, 256, 0, stream>>>(w_qkv, wbuf, x, xt);
    qkv_k<<<dim3(8, 8, 12), 256, 0, stream>>>(wbuf, xt, qt, ktr, vvr);
    attn_k<<<dim3(64, 8), 512, 0, stream>>>(qt, ktr, vvr, ao2);
    psum_k<<<2048, 64, 0, stream>>>(ao2, p1, p2);
    proj_k<<<dim3(8, 32, 4), 256, 0, stream>>>(ao2, w_proj, w_lp, b_lp, gamma, beta, p1, p2, y);
}

// Round 24
// 72.628 us; speedup vs baseline: 1.1029x; 1.0065x over previous
//
#include <hip/hip_runtime.h>
#include <hip/hip_bf16.h>

// attention scale folded with log2(e): softmax exp(x) = exp2(x * log2e)
#define ATT_SCALE_L2E 0.2550322540f   // 32^-0.5 * log2(e)

typedef __attribute__((ext_vector_type(8))) short bf16x8;
typedef __attribute__((ext_vector_type(4))) short bf16x4;
typedef __attribute__((ext_vector_type(4))) float f32x4;
typedef __attribute__((ext_vector_type(16))) float f32x16;
typedef __attribute__((ext_vector_type(4))) int i32x4;

#define MFMA16(a, b, c) __builtin_amdgcn_mfma_f32_16x16x32_bf16(a, b, c, 0, 0, 0)
#define MFMA32(a, b, c) __builtin_amdgcn_mfma_f32_32x32x16_bf16(a, b, c, 0, 0, 0)

__device__ inline short f2b(float f) {
    return __builtin_bit_cast(short, __float2bfloat16(f));
}

// packed f32x2 -> bf16x2 in one instruction
__device__ inline int cvt_pk(float a, float b) {
    int r;
    asm("v_cvt_pk_bf16_f32 %0, %1, %2" : "=v"(r) : "v"(a), "v"(b));
    return r;
}

// ---------------------------------------------------------------------------
// K0: fused prep — blocks 0..95: w_qkv fp32->bf16 (wconv body);
//     blocks 96..351: downsample+transpose+bf16 xt[b][n][c] (xt body).
// (r22, verified: 78.6 -> 74.4 via launch fusion + overlap)
// ---------------------------------------------------------------------------
__global__ __launch_bounds__(256) void prep_k(const float* __restrict__ w,
                                              short* __restrict__ wb,
                                              const float* __restrict__ x,
                                              short* __restrict__ xt) {
    int bx = blockIdx.x;
    int t = threadIdx.x;
    if (bx < 96) {
        int i0 = (bx * 256 + t) * 8;
        float4 lo = *(const float4*)(w + i0);
        float4 hi = *(const float4*)(w + i0 + 4);
        bf16x8 o;
        o[0] = f2b(lo.x); o[1] = f2b(lo.y); o[2] = f2b(lo.z); o[3] = f2b(lo.w);
        o[4] = f2b(hi.x); o[5] = f2b(hi.y); o[6] = f2b(hi.z); o[7] = f2b(hi.w);
        *(bf16x8*)(wb + i0) = o;
    } else {
        int idx = bx - 96;              // 0..255
        int b = idx >> 5;               // 0..7
        int xn = idx & 31;              // 0..31
        int n = xn * 32 + (t >> 3);
        const float* xb = x + (size_t)b * 1048576 + (n >> 5) * 128 + (n & 31) * 2;
        short* dst = xt + ((size_t)b * 1024 + n) * 256;
#pragma unroll
        for (int it = 0; it < 4; ++it) {
            int c = (t & 7) * 8 + it * 64;
            bf16x8 o;
#pragma unroll
            for (int j = 0; j < 8; ++j) o[j] = f2b(xb[(size_t)(c + j) * 4096]);
            *(bf16x8*)(dst + c) = o;
        }
    }
}

// ---------------------------------------------------------------------------
// K1: QKV MFMA GEMM (LDS-free main loop), epilogue transpose (r11, verified).
// ---------------------------------------------------------------------------
__global__ __launch_bounds__(256) void qkv_k(const short* __restrict__ wb,
                                             const short* __restrict__ xt,
                                             short* __restrict__ qt,
                                             short* __restrict__ ktr,
                                             short* __restrict__ vvr) {
    int b = blockIdx.x;
    int ntile = blockIdx.y * 128;
    int otile = blockIdx.z * 64;
    int t = threadIdx.x;
    int w = t >> 6, l = t & 63, g = l >> 4, li = l & 15;
    int oh = (w & 1) * 32, mh = (w >> 1) * 64;
    int o_base = otile + oh;
    int head = o_base / 96;
    int role = (o_base >> 5) % 3;  // 0=q 1=k 2=v
    size_t bh = (size_t)b * 8 + head;

    const short* arow = wb + (size_t)o_base * 256;
    const short* brow = xt + ((size_t)b * 1024 + ntile + mh) * 256;

    f32x4 zero = {0.f, 0.f, 0.f, 0.f};
    f32x4 acc[2][4];
#pragma unroll
    for (int og = 0; og < 2; ++og)
#pragma unroll
        for (int mg = 0; mg < 4; ++mg) acc[og][mg] = zero;

#pragma unroll
    for (int kc = 0; kc < 256; kc += 32) {
        bf16x8 af[2], bf_[4];
#pragma unroll
        for (int og = 0; og < 2; ++og)
            af[og] = *(const bf16x8*)(arow + (size_t)(og * 16 + li) * 256 + kc + 8 * g);
#pragma unroll
        for (int mg = 0; mg < 4; ++mg)
            bf_[mg] = *(const bf16x8*)(brow + (size_t)(mg * 16 + li) * 256 + kc + 8 * g);
#pragma unroll
        for (int og = 0; og < 2; ++og)
#pragma unroll
            for (int mg = 0; mg < 4; ++mg)
                acc[og][mg] = MFMA16(af[og], bf_[mg], acc[og][mg]);
    }

    __shared__ short Tl[4][32][64];
    short (*Tw)[64] = Tl[w];
    float sc = (role == 0) ? ATT_SCALE_L2E : 1.f;

#pragma unroll
    for (int og = 0; og < 2; ++og)
#pragma unroll
        for (int mg = 0; mg < 4; ++mg)
#pragma unroll
            for (int r = 0; r < 4; ++r) {
                int op = og * 16 + 4 * g + r;
                int qp = (op >> 3) & 3;
                Tw[op][(mg * 16 + li) ^ (qp << 4)] = f2b(acc[og][mg][r] * sc);
            }
    __syncthreads();

    if (role == 0) {
#pragma unroll
        for (int it = 0; it < 4; ++it) {
            int s = it * 64 + l;
            int dq = (l & 3) * 8;
            int n = s >> 2;
            int q2 = dq >> 3;
            bf16x8 vo;
#pragma unroll
            for (int j = 0; j < 8; ++j)
                vo[j] = Tw[dq + j][n ^ (q2 << 4)];
            *(bf16x8*)(qt + ((size_t)bh * 1024 + ntile + mh + n) * 32 + dq) = vo;
        }
    } else if (role == 1) {
        int base_jb = (ntile + mh) >> 5;
#pragma unroll
        for (int it = 0; it < 4; ++it) {
            int s = it * 64 + l;
            int il2 = s & 31;
            int combo = (s >> 5) & 3;
            int jbr = s >> 7;
            int dq = combo * 8;
            int n_rel = jbr * 32 + il2;
            bf16x8 vo;
#pragma unroll
            for (int j = 0; j < 8; ++j)
                vo[j] = Tw[dq + j][n_rel ^ (combo << 4)];
            *(bf16x8*)(ktr + (size_t)bh * 32768 +
                       (size_t)(base_jb + jbr) * 1024 + combo * 256 + il2 * 8) = vo;
        }
    } else {
        int base_jb = (ntile + mh) >> 5;
#pragma unroll
        for (int it = 0; it < 4; ++it) {
            int s = it * 64 + l;
            int il2 = s & 31;
            int combo = (s >> 5) & 3;
            int jbr = s >> 7;
            int pan = combo >> 1, hi2 = combo & 1;
            int q2 = (il2 >> 3) & 3;
            int bn = jbr * 32 + pan * 16 + 4 * hi2;
            bf16x8 vo;
#pragma unroll
            for (int j = 0; j < 4; ++j) vo[j] = Tw[il2][(bn + j) ^ (q2 << 4)];
#pragma unroll
            for (int j = 0; j < 4; ++j) vo[4 + j] = Tw[il2][(bn + 8 + j) ^ (q2 << 4)];
            *(bf16x8*)(vvr + (size_t)bh * 32768 +
                       (size_t)(base_jb + jbr) * 1024 + combo * 256 + il2 * 8) = vo;
        }
    }
}

// ---------------------------------------------------------------------------
// K2: attention (r11, verified best). Output ao2[b][c][n].
// ---------------------------------------------------------------------------
__global__ __launch_bounds__(512) void attn_k(const short* __restrict__ qt,
                                              const short* __restrict__ ktr,
                                              const short* __restrict__ vvr,
                                              float* __restrict__ ao2) {
    int bh = blockIdx.x;
    int b = bh >> 3, h = bh & 7;
    int t = threadIdx.x;
    int w = t >> 6, l = t & 63;
    int il = l & 31, hi = l >> 5;
    int wq = w & 3, jh = w >> 2;
    int ibase = blockIdx.y * 128 + wq * 32;

    const short* qtb = qt + (size_t)bh * 32768;
    const short* kbase = ktr + (size_t)bh * 32768 + jh * 16384 + hi * 256 + il * 8;
    const short* vbase = vvr + (size_t)bh * 32768 + jh * 16384 + hi * 256 + il * 8;

    bf16x8 qf0 = *(const bf16x8*)(qtb + (size_t)(ibase + il) * 32 + 8 * hi);
    bf16x8 qf1 = *(const bf16x8*)(qtb + (size_t)(ibase + il) * 32 + 16 + 8 * hi);

    f32x16 zero16 = {0.f,0.f,0.f,0.f,0.f,0.f,0.f,0.f,0.f,0.f,0.f,0.f,0.f,0.f,0.f,0.f};
    f32x16 oacc = zero16;
    float lr0 = 0.f, lr1 = 0.f, lr2 = 0.f, lr3 = 0.f;

#pragma unroll 2
    for (int jb = 0; jb < 16; ++jb) {
        const short* kp = kbase + (size_t)jb * 1024;
        const short* vp = vbase + (size_t)jb * 1024;
        bf16x8 kf0 = *(const bf16x8*)(kp);
        bf16x8 kf1 = *(const bf16x8*)(kp + 512);
        f32x16 s = MFMA32(kf0, qf0, zero16);
        s = MFMA32(kf1, qf1, s);

        float p[16];
#pragma unroll
        for (int r = 0; r < 16; ++r) p[r] = exp2f(s[r]);
        lr0 += p[0] + p[4] + p[8]  + p[12];
        lr1 += p[1] + p[5] + p[9]  + p[13];
        lr2 += p[2] + p[6] + p[10] + p[14];
        lr3 += p[3] + p[7] + p[11] + p[15];

        i32x4 fa, fb;
        fa[0] = cvt_pk(p[0], p[1]);   fa[1] = cvt_pk(p[2], p[3]);
        fa[2] = cvt_pk(p[4], p[5]);   fa[3] = cvt_pk(p[6], p[7]);
        fb[0] = cvt_pk(p[8], p[9]);   fb[1] = cvt_pk(p[10], p[11]);
        fb[2] = cvt_pk(p[12], p[13]); fb[3] = cvt_pk(p[14], p[15]);
        bf16x8 pfa = __builtin_bit_cast(bf16x8, fa);
        bf16x8 pfb = __builtin_bit_cast(bf16x8, fb);

        bf16x8 vfa = *(const bf16x8*)(vp);
        bf16x8 vfb = *(const bf16x8*)(vp + 512);
        oacc = MFMA32(vfa, pfa, oacc);
        oacc = MFMA32(vfb, pfb, oacc);
    }

    float lrun = (lr0 + lr1) + (lr2 + lr3);

    // ---- fp32 combine of the two j-halves through LDS ----
    __shared__ float OB[4][64][20];
    __shared__ float LB[4][32];

    if (jh == 1) {
#pragma unroll
        for (int r4 = 0; r4 < 4; ++r4) {
            float4 v = {oacc[r4 * 4], oacc[r4 * 4 + 1], oacc[r4 * 4 + 2], oacc[r4 * 4 + 3]};
            *(float4*)&OB[wq][l][r4 * 4] = v;
        }
        float tu = lrun + __shfl_xor(lrun, 32);
        if (hi == 0) LB[wq][il] = tu;
    }
    __syncthreads();
    if (jh == 0) {
#pragma unroll
        for (int r = 0; r < 16; ++r) oacc[r] += OB[wq][l][r];
        float tl = lrun + __shfl_xor(lrun, 32);
        float inv = 1.f / (tl + LB[wq][il]);

        float* base = ao2 + ((size_t)(b * 256 + h * 32)) * 1024 + ibase + il;
#pragma unroll
        for (int r = 0; r < 16; ++r) {
            int d = (r & 3) + 8 * (r >> 2) + 4 * hi;
            base[(size_t)d * 1024] = oacc[r] * inv;
        }
    }
}

// ---------------------------------------------------------------------------
// K3: per-(b,c) sum/sumsq of ao2 rows (contiguous 1024 floats). 1 wave/row.
// ---------------------------------------------------------------------------
__global__ __launch_bounds__(64) void psum_k(const float* __restrict__ ao2,
                                             float* __restrict__ p1,
                                             float* __restrict__ p2) {
    int row = blockIdx.x;
    const float* base = ao2 + (size_t)row * 1024;
    int l = threadIdx.x;
    float s = 0.f, q = 0.f;
#pragma unroll
    for (int t = 0; t < 4; ++t) {
        float4 v = *(const float4*)(base + l * 4 + t * 256);
        s += v.x + v.y + v.z + v.w;
        q += v.x * v.x + v.y * v.y + v.z * v.z + v.w * v.w;
    }
#pragma unroll
    for (int o = 1; o < 64; o <<= 1) {
        s += __shfl_xor(s, o);
        q += __shfl_xor(q, o);
    }
    if (l == 0) { p1[row] = s; p2[row] = q; }
}

// ---------------------------------------------------------------------------
// K5: MFMA projection GEMM (r11 body) with the verified stats_k body inlined
// as a per-block prologue (r23, verified: 74.4 -> 73.1).
// Grid (b, mt, otile): linear%8 = b -> per-XCD ao2[b] locality.
// ---------------------------------------------------------------------------
__global__ __launch_bounds__(256) void proj_k(const float* __restrict__ ao2,
                                              const float* __restrict__ wp,
                                              const float* __restrict__ wlp,
                                              const float* __restrict__ blp,
                                              const float* __restrict__ gamma,
                                              const float* __restrict__ beta,
                                              const float* __restrict__ p1,
                                              const float* __restrict__ p2,
                                              float* __restrict__ y) {
    int b = blockIdx.x;
    int mt = blockIdx.y;
    int otile = blockIdx.z * 64;
    int t = threadIdx.x;

    // ---- stats prologue (verbatim stats_k body; outputs via shared mss) ----
    __shared__ float red1[256], red2[256];
    __shared__ float mss[2];
    {
        int c = t;
        float s = p1[b * 256 + c];
        float q = p2[b * 256 + c];
        float u0 = wlp[c * 4], u1 = wlp[c * 4 + 1], u2 = wlp[c * 4 + 2], u3 = wlp[c * 4 + 3];
        float S1 = u0 + u1 + u2 + u3, S2 = u0 * u0 + u1 * u1 + u2 * u2 + u3 * u3;
        float bl = blp[c];
        red1[c] = S1 * s + 4096.f * bl;
        red2[c] = S2 * q + 2.f * bl * S1 * s + 4096.f * bl * bl;
        __syncthreads();
        for (int o = 128; o > 0; o >>= 1) {
            if (c < o) { red1[c] += red1[c + o]; red2[c] += red2[c + o]; }
            __syncthreads();
        }
        if (c == 0) {
            const float N = 1048576.f;
            float mu = red1[0] / N;
            float var = red2[0] / N - mu * mu;
            mss[0] = mu;
            mss[1] = rsqrtf(var + 1e-5f);
        }
        __syncthreads();
    }
    float mu = mss[0], rs = mss[1];

    __shared__ short As[64][40];
    __shared__ short Bs[128][40];

    int w = t >> 6, l = t & 63, g = l >> 4, li = l & 15;
    int oh = (w >> 1) * 32, mh = (w & 1) * 64;

    f32x4 zero = {0.f, 0.f, 0.f, 0.f};
    f32x4 acc[2][4];
#pragma unroll
    for (int og = 0; og < 2; ++og)
#pragma unroll
        for (int mg = 0; mg < 4; ++mg) acc[og][mg] = zero;

    int so = t >> 2, sc = (t & 3) * 8;
    int bc = t & 31, bm = (t >> 5) * 16;
    int p = t >> 7;
    int wbase = bm & 63;

    for (int kc = 0; kc < 256; kc += 32) {
        const float* wrow = wp + (size_t)(otile + so) * 256 + kc + sc;
#pragma unroll
        for (int j = 0; j < 8; ++j) As[so][sc + j] = f2b(wrow[j]);
        int c = kc + bc;
        float Ac = gamma[c] * rs;
        float Dc = Ac * (blp[c] - mu) + beta[c];
        float w0 = Ac * wlp[c * 4 + p * 2 + 0];
        float w1 = Ac * wlp[c * 4 + p * 2 + 1];
        const float* arow = ao2 + ((size_t)(b * 256 + c)) * 1024 + mt * 32 + (wbase >> 1);
        float4 a0 = *(const float4*)arow;
        float4 a1 = *(const float4*)(arow + 4);
        float av[8] = {a0.x, a0.y, a0.z, a0.w, a1.x, a1.y, a1.z, a1.w};
#pragma unroll
        for (int k = 0; k < 8; ++k) {
            Bs[bm + 2 * k    ][bc] = f2b(w0 * av[k] + Dc);
            Bs[bm + 2 * k + 1][bc] = f2b(w1 * av[k] + Dc);
        }
        __syncthreads();
        bf16x8 af[2], bf_[4];
#pragma unroll
        for (int og = 0; og < 2; ++og) af[og] = *(const bf16x8*)&As[oh + og * 16 + li][8 * g];
#pragma unroll
        for (int mg = 0; mg < 4; ++mg) bf_[mg] = *(const bf16x8*)&Bs[mh + mg * 16 + li][8 * g];
#pragma unroll
        for (int og = 0; og < 2; ++og)
#pragma unroll
            for (int mg = 0; mg < 4; ++mg) acc[og][mg] = MFMA16(af[og], bf_[mg], acc[og][mg]);
        __syncthreads();
    }

#pragma unroll
    for (int og = 0; og < 2; ++og) {
        int o = otile + oh + og * 16 + 4 * g;
#pragma unroll
        for (int mg = 0; mg < 4; ++mg) {
            int m = mt * 128 + mh + mg * 16 + li;
            float* yp = y + ((size_t)b * 256 + o) * 4096 + m;
#pragma unroll
            for (int r = 0; r < 4; ++r) yp[(size_t)r * 4096] = acc[og][mg][r];
        }
    }
}

extern "C" void kernel_launch(void* const* d_in, const int* in_sizes, int n_in,
                              void* d_out, int out_size, void* d_ws, size_t ws_size,
                              hipStream_t stream) {
    const float* x      = (const float*)d_in[0];
    const float* w_qkv  = (const float*)d_in[1];
    const float* w_lp   = (const float*)d_in[2];
    const float* b_lp   = (const float*)d_in[3];
    const float* gamma  = (const float*)d_in[4];
    const float* beta   = (const float*)d_in[5];
    const float* w_proj = (const float*)d_in[6];
    float* y = (float*)d_out;

    short* qt   = (short*)d_out;        // 2097152 shorts
    short* ktr  = qt + 2097152;
    short* vvr  = ktr + 2097152;
    short* xt   = vvr + 2097152;
    short* wbuf = xt + 2097152;

    float* ao2   = (float*)d_ws;        // 2097152 floats [b][c][n]
    float* p1    = ao2 + 2097152;       // 2048
    float* p2    = p1 + 2048;           // 2048

    prep_k<<<352, 256, 0, stream>>>(w_qkv, wbuf, x, xt);
    qkv_k<<<dim3(8, 8, 12), 256, 0, stream>>>(wbuf, xt, qt, ktr, vvr);
    attn_k<<<dim3(64, 8), 512, 0, stream>>>(qt, ktr, vvr, ao2);
    psum_k<<<2048, 64, 0, stream>>>(ao2, p1, p2);
    proj_k<<<dim3(8, 32, 4), 256, 0, stream>>>(ao2, w_proj, w_lp, b_lp, gamma, beta, p1, p2, y);
}